// Round 6
// baseline (4638.796 us; speedup 1.0000x reference)
//
#include <hip/hip_runtime.h>
#include <cmath>

#define Bb   32
#define Tt   512
#define INd  128
#define RES  2048
#define OUTd 64

#define BM 64
#define BN 64
#define BK 16

typedef unsigned short u16;
typedef __attribute__((ext_vector_type(4))) unsigned short u16x4;
typedef __attribute__((ext_vector_type(8))) unsigned short u16x8;
typedef __attribute__((ext_vector_type(8))) short bf8;
typedef __attribute__((ext_vector_type(4))) float f32x4;

// fp32 = bf16 hi (RNE) + bf16 lo (trunc residual); |err| <= 2^-17 |a|
__device__ __forceinline__ void splitf(float a, u16& h, u16& l) {
    unsigned u = __float_as_uint(a);
    unsigned r = (u + 0x7fffu + ((u >> 16) & 1u)) & 0xffff0000u;
    h = (u16)(r >> 16);
    float d = a - __uint_as_float(r);
    l = (u16)(__float_as_uint(d) >> 16);
}
__device__ __forceinline__ float bf2f(u16 h) {
    return __uint_as_float((unsigned)h << 16);
}
__device__ __forceinline__ void split8(const float4& a, const float4& b,
                                       u16x8& h, u16x8& l) {
    u16 hh, ll;
    splitf(a.x, hh, ll); h[0] = hh; l[0] = ll;
    splitf(a.y, hh, ll); h[1] = hh; l[1] = ll;
    splitf(a.z, hh, ll); h[2] = hh; l[2] = ll;
    splitf(a.w, hh, ll); h[3] = hh; l[3] = ll;
    splitf(b.x, hh, ll); h[4] = hh; l[4] = ll;
    splitf(b.y, hh, ll); h[5] = hh; l[5] = ll;
    splitf(b.z, hh, ll); h[6] = hh; l[6] = ll;
    splitf(b.w, hh, ll); h[7] = hh; l[7] = ll;
}

#define MICRO(SA, SB)                                                           \
  do {                                                                          \
    _Pragma("unroll")                                                           \
    for (int kk = 0; kk < BK; ++kk) {                                           \
      const float4 a4 = *(const float4*)&SA[kk][ty << 2];                       \
      const float4 b4 = *(const float4*)&SB[kk][tx << 2];                       \
      acc[0][0] += a4.x*b4.x; acc[0][1] += a4.x*b4.y;                           \
      acc[0][2] += a4.x*b4.z; acc[0][3] += a4.x*b4.w;                           \
      acc[1][0] += a4.y*b4.x; acc[1][1] += a4.y*b4.y;                           \
      acc[1][2] += a4.y*b4.z; acc[1][3] += a4.y*b4.w;                           \
      acc[2][0] += a4.z*b4.x; acc[2][1] += a4.z*b4.y;                           \
      acc[2][2] += a4.z*b4.z; acc[2][3] += a4.z*b4.w;                           \
      acc[3][0] += a4.w*b4.x; acc[3][1] += a4.w*b4.y;                           \
      acc[3][2] += a4.w*b4.z; acc[3][3] += a4.w*b4.w;                           \
    }                                                                           \
  } while (0)

// 128x128 tile, K=32 slice, bf16x3. LDS row stride 40 u16 (80B: 16B-aligned,
// 2-way banks = free). Layout verified in R5 (passed).
#define MFMA_TILE()                                                              \
  do {                                                                           \
    bf8 aH[4], aL[4], bH[4], bL[4];                                              \
    _Pragma("unroll")                                                            \
    for (int i = 0; i < 4; ++i) {                                                \
      const int ar = (wm*64 + i*16 + l15)*40 + quad*8;                           \
      aH[i] = *(const bf8*)&Ah[ar]; aL[i] = *(const bf8*)&Al[ar];                \
      const int br = (wn*64 + i*16 + l15)*40 + quad*8;                           \
      bH[i] = *(const bf8*)&Bh[br]; bL[i] = *(const bf8*)&Bl[br];                \
    }                                                                            \
    _Pragma("unroll")                                                            \
    for (int i = 0; i < 4; ++i)                                                  \
      _Pragma("unroll")                                                          \
      for (int j = 0; j < 4; ++j) {                                              \
        acc[i][j] = __builtin_amdgcn_mfma_f32_16x16x32_bf16(aH[i], bH[j], acc[i][j], 0, 0, 0); \
        acc[i][j] = __builtin_amdgcn_mfma_f32_16x16x32_bf16(aH[i], bL[j], acc[i][j], 0, 0, 0); \
        acc[i][j] = __builtin_amdgcn_mfma_f32_16x16x32_bf16(aL[i], bH[j], acc[i][j], 0, 0, 0); \
      }                                                                          \
  } while (0)

// Transpose + split weights: in (K x N fp32) -> outH/outL (N x K bf16).
__global__ __launch_bounds__(256)
void tconv_kernel(const float* __restrict__ in, u16* __restrict__ outH,
                  u16* __restrict__ outL, int K, int N)
{
    __shared__ float T[64][65];
    const int n0 = blockIdx.x * 64, k0 = blockIdx.y * 64;
    const int t = threadIdx.x;
    const int r = t >> 2, c0 = (t & 3) * 16;
#pragma unroll
    for (int i = 0; i < 4; ++i) {
        const float4 v = *(const float4*)&in[(size_t)(k0 + r) * N + n0 + c0 + 4*i];
        T[r][c0 + 4*i + 0] = v.x; T[r][c0 + 4*i + 1] = v.y;
        T[r][c0 + 4*i + 2] = v.z; T[r][c0 + 4*i + 3] = v.w;
    }
    __syncthreads();
    const int n = t >> 2, ck = (t & 3) * 16;
    u16x8 h0, h1, l0, l1;
#pragma unroll
    for (int i = 0; i < 8; ++i) { u16 h, l; splitf(T[ck + i][n], h, l); h0[i] = h; l0[i] = l; }
#pragma unroll
    for (int i = 0; i < 8; ++i) { u16 h, l; splitf(T[ck + 8 + i][n], h, l); h1[i] = h; l1[i] = l; }
    const size_t ob = (size_t)(n0 + n) * K + k0 + ck;
    *(u16x8*)&outH[ob] = h0; *(u16x8*)&outH[ob + 8] = h1;
    *(u16x8*)&outL[ob] = l0; *(u16x8*)&outL[ob + 8] = l1;
}

// Reservoir step on bf16 hi/lo state planes (RS layout: row = b*512 + 4w + class).
// state' = 0.7*(h+l) + 0.3*sin((h+l)@Wres + x@Win); pure u16x8 staging in K-loop.
__global__ __launch_bounds__(256)
void step_mfma_kernel(u16* __restrict__ Sh, u16* __restrict__ Sl,
                      const float* __restrict__ X,
                      const u16* __restrict__ WTh, const u16* __restrict__ WTl,
                      const u16* __restrict__ WinTh, const u16* __restrict__ WinTl,
                      int cin, int cout, int s)
{
    __shared__ u16 Ah[128 * 40], Al[128 * 40], Bh[128 * 40], Bl[128 * 40];
    const int tid = threadIdx.x;
    const int bid = blockIdx.x;
    // XCD swizzle: blocks sharing a W col-tile land on one XCD (bid%8 heuristic)
    const int q0  = (((bid & 7) << 1) | (bid >> 8)) * 128;
    const int b   = (bid >> 3) & 31;
    const int bofs = b * Tt;
    const int wid = tid >> 6, lane = tid & 63;
    const int wm = wid & 1, wn = wid >> 1;
    const int l15 = lane & 15, quad = lane >> 4;
    const int row  = tid & 127;     // staging row within 128-tile
    const int pick = tid >> 7;      // 0: A-operand (state), 1: B-operand (W)

    f32x4 acc[4][4];
    const f32x4 zz = {0.f, 0.f, 0.f, 0.f};
#pragma unroll
    for (int i = 0; i < 4; ++i)
#pragma unroll
        for (int j = 0; j < 4; ++j) acc[i][j] = zz;

    u16* dH = (pick ? Bh : Ah) + row * 40;
    u16* dL = (pick ? Bl : Al) + row * 40;

    if (s > 0) {
        const size_t gr = pick ? (size_t)(q0 + row) * RES
                               : (size_t)(bofs + 4 * row + cin) * RES;
        const u16* gH = (pick ? WTh : Sh) + gr;
        const u16* gL = (pick ? WTl : Sl) + gr;
        for (int k0 = 0; k0 < RES; k0 += 32) {
            *(u16x8*)&dH[0]  = *(const u16x8*)&gH[k0 + 0];
            *(u16x8*)&dH[8]  = *(const u16x8*)&gH[k0 + 8];
            *(u16x8*)&dH[16] = *(const u16x8*)&gH[k0 + 16];
            *(u16x8*)&dH[24] = *(const u16x8*)&gH[k0 + 24];
            *(u16x8*)&dL[0]  = *(const u16x8*)&gL[k0 + 0];
            *(u16x8*)&dL[8]  = *(const u16x8*)&gL[k0 + 8];
            *(u16x8*)&dL[16] = *(const u16x8*)&gL[k0 + 16];
            *(u16x8*)&dL[24] = *(const u16x8*)&gL[k0 + 24];
            __syncthreads();
            MFMA_TILE();
            __syncthreads();
        }
    }

    // input projection: K=128 over x[b, 4w+s-2, :] @ Win (split on the fly, 4 iters)
    for (int k0 = 0; k0 < INd; k0 += 32) {
        if (pick == 0) {
            const int t = 4 * row + s - 2;
            u16x8 h0 = {0,0,0,0,0,0,0,0}, h1 = h0, h2 = h0, h3 = h0;
            u16x8 l0 = h0, l1 = h0, l2 = h0, l3 = h0;
            if (t >= 0) {
                const float* xr = X + (size_t)(bofs + t) * INd + k0;
                const float4 f0 = *(const float4*)&xr[0];
                const float4 f1 = *(const float4*)&xr[4];
                const float4 f2 = *(const float4*)&xr[8];
                const float4 f3 = *(const float4*)&xr[12];
                const float4 f4 = *(const float4*)&xr[16];
                const float4 f5 = *(const float4*)&xr[20];
                const float4 f6 = *(const float4*)&xr[24];
                const float4 f7 = *(const float4*)&xr[28];
                split8(f0, f1, h0, l0); split8(f2, f3, h1, l1);
                split8(f4, f5, h2, l2); split8(f6, f7, h3, l3);
            }
            *(u16x8*)&dH[0] = h0;  *(u16x8*)&dH[8] = h1;
            *(u16x8*)&dH[16] = h2; *(u16x8*)&dH[24] = h3;
            *(u16x8*)&dL[0] = l0;  *(u16x8*)&dL[8] = l1;
            *(u16x8*)&dL[16] = l2; *(u16x8*)&dL[24] = l3;
        } else {
            const size_t gr = (size_t)(q0 + row) * INd + k0;
            *(u16x8*)&dH[0]  = *(const u16x8*)&WinTh[gr];
            *(u16x8*)&dH[8]  = *(const u16x8*)&WinTh[gr + 8];
            *(u16x8*)&dH[16] = *(const u16x8*)&WinTh[gr + 16];
            *(u16x8*)&dH[24] = *(const u16x8*)&WinTh[gr + 24];
            *(u16x8*)&dL[0]  = *(const u16x8*)&WinTl[gr];
            *(u16x8*)&dL[8]  = *(const u16x8*)&WinTl[gr + 8];
            *(u16x8*)&dL[16] = *(const u16x8*)&WinTl[gr + 16];
            *(u16x8*)&dL[24] = *(const u16x8*)&WinTl[gr + 24];
        }
        __syncthreads();
        MFMA_TILE();
        __syncthreads();
    }

    // epilogue
#pragma unroll
    for (int i = 0; i < 4; ++i)
#pragma unroll
        for (int j = 0; j < 4; ++j)
#pragma unroll
            for (int rg = 0; rg < 4; ++rg) {
                const int rr = wm * 64 + i * 16 + quad * 4 + rg;
                const int q  = q0 + wn * 64 + j * 16 + l15;
                float v = acc[i][j][rg];
                float prev = 0.f;
                if (s > 0) {
                    const size_t pi = (size_t)(bofs + 4 * rr + cin) * RES + q;
                    prev = bf2f(Sh[pi]) + bf2f(Sl[pi]);
                }
                v = 0.7f * prev + 0.3f * sinf(v);
                u16 vh, vl; splitf(v, vh, vl);
                const size_t oi = (size_t)(bofs + 4 * rr + cout) * RES + q;
                Sh[oi] = vh; Sl[oi] = vl;
            }
}

// Gram on bf16 planes: A[b] = (Sh+Sl)(Sh+Sl)^T + ones + reg*I, bf16x3.
__global__ __launch_bounds__(256)
void gram_mfma_kernel(const u16* __restrict__ Sh, const u16* __restrict__ Sl,
                      float* __restrict__ A, const float* __restrict__ lam)
{
    __shared__ u16 Ah[128 * 40], Al[128 * 40], Bh[128 * 40], Bl[128 * 40];
    const int tid = threadIdx.x;
    const int bt  = blockIdx.y;
    int ti = 0, rem = (int)blockIdx.x;
    while (rem >= 4 - ti) { rem -= 4 - ti; ++ti; }
    const int tj = ti + rem;
    const int n0 = ti * 128, m0 = tj * 128;
    const int bofs = bt * Tt;

    const int wid = tid >> 6, lane = tid & 63;
    const int wm = wid & 1, wn = wid >> 1;
    const int l15 = lane & 15, quad = lane >> 4;
    const int row  = tid & 127;
    const int pick = tid >> 7;

    f32x4 acc[4][4];
    const f32x4 zz = {0.f, 0.f, 0.f, 0.f};
#pragma unroll
    for (int i = 0; i < 4; ++i)
#pragma unroll
        for (int j = 0; j < 4; ++j) acc[i][j] = zz;

    u16* dH = (pick ? Bh : Ah) + row * 40;
    u16* dL = (pick ? Bl : Al) + row * 40;
    const size_t gr = (size_t)(bofs + (pick ? m0 : n0) + row) * RES;
    const u16* gH = Sh + gr;
    const u16* gL = Sl + gr;

    for (int k0 = 0; k0 < RES; k0 += 32) {
        *(u16x8*)&dH[0]  = *(const u16x8*)&gH[k0 + 0];
        *(u16x8*)&dH[8]  = *(const u16x8*)&gH[k0 + 8];
        *(u16x8*)&dH[16] = *(const u16x8*)&gH[k0 + 16];
        *(u16x8*)&dH[24] = *(const u16x8*)&gH[k0 + 24];
        *(u16x8*)&dL[0]  = *(const u16x8*)&gL[k0 + 0];
        *(u16x8*)&dL[8]  = *(const u16x8*)&gL[k0 + 8];
        *(u16x8*)&dL[16] = *(const u16x8*)&gL[k0 + 16];
        *(u16x8*)&dL[24] = *(const u16x8*)&gL[k0 + 24];
        __syncthreads();
        MFMA_TILE();
        __syncthreads();
    }
    const float reg = log1pf(expf(lam[0]));
    float* Ab = A + (size_t)bt * 512 * 512;
#pragma unroll
    for (int i = 0; i < 4; ++i)
#pragma unroll
        for (int j = 0; j < 4; ++j)
#pragma unroll
            for (int rg = 0; rg < 4; ++rg) {
                const int nn = n0 + wm * 64 + i * 16 + quad * 4 + rg;
                const int mm = m0 + wn * 64 + j * 16 + l15;
                float val = acc[i][j][rg] + 1.0f;
                if (nn == mm) val += reg;
                Ab[(size_t)nn * 512 + mm] = val;
                Ab[(size_t)mm * 512 + nn] = val;
            }
}

// Diag-block Cholesky (64x64) + inverse, one wave per batch. Writes L_kk and
// W = inv(L_kk) (+ transpose) used by trsm and fb_solve2.
__global__ __launch_bounds__(64)
void chol_diag_inv_kernel(float* __restrict__ Aall, float* __restrict__ Winv,
                          float* __restrict__ WinvT, int k)
{
    __shared__ float P[64][65];
    __shared__ float W[64][65];
    const int b = blockIdx.x, c = threadIdx.x;
    float* A = Aall + (size_t)b * 512 * 512;
    const int j0 = 64 * k;

    for (int m = 0; m < 64; m += 4) {
        const float4 v = *(const float4*)(A + (size_t)(j0 + c) * 512 + j0 + m);
        P[c][m] = v.x; P[c][m+1] = v.y; P[c][m+2] = v.z; P[c][m+3] = v.w;
    }
    __syncthreads();
    for (int j = 0; j < 64; ++j) {
        const float d = sqrtf(P[j][j]);
        if (c >= j) P[c][j] = (c == j) ? d : P[c][j] / d;
        __syncthreads();
        const float pj = (c > j) ? P[c][j] : 0.f;
        for (int m = j + 1; m <= c; ++m) P[c][m] -= pj * P[m][j];
        __syncthreads();
    }
    // W = inv(L): thread c owns column c, no cross-thread deps
    for (int j = 0; j < 64; ++j) {
        float sv = (j == c) ? 1.f : 0.f;
        for (int m = c; m < j; ++m) sv -= P[j][m] * W[m][c];
        W[j][c] = (j >= c) ? sv / P[j][j] : 0.f;
    }
    __syncthreads();
    for (int m = 0; m < 64; m += 4)
        *(float4*)(A + (size_t)(j0 + c) * 512 + j0 + m) =
            make_float4(P[c][m], P[c][m+1], P[c][m+2], P[c][m+3]);
    float* Wo  = Winv  + ((size_t)b * 8 + k) * 64 * 64;
    float* WoT = WinvT + ((size_t)b * 8 + k) * 64 * 64;
    for (int j = 0; j < 64; ++j) Wo[(size_t)j * 64 + c] = W[j][c];
    for (int m = 0; m < 64; m += 4)
        *(float4*)(WoT + (size_t)c * 64 + m) =
            make_float4(W[m][c], W[m+1][c], W[m+2][c], W[m+3][c]);
}

// Panel TRSM via inverse: L[i0.., k] = A[i0.., k] @ W^T  (GEMM 64x64x64)
__global__ __launch_bounds__(256)
void trsm_kernel(float* __restrict__ Aall, const float* __restrict__ WinvT, int k)
{
    __shared__ float St[BK][BM + 4];
    __shared__ float Wt[BK][BN + 4];
    float* A = Aall + (size_t)blockIdx.y * 512 * 512;
    const float* WT = WinvT + ((size_t)blockIdx.y * 8 + k) * 64 * 64;
    const int i0 = (k + 1 + blockIdx.x) * 64, p0 = k * 64;
    const int tid = threadIdx.x;
    const int li = tid >> 2, lk = (tid & 3) << 2;
    const int wk = tid >> 4, wq = (tid & 15) << 2;
    const int ty = tid >> 4, tx = tid & 15;
    float acc[4][4] = {};
    for (int k0 = 0; k0 < 64; k0 += BK) {
        const float4 u = *(const float4*)(A + (size_t)(i0 + li) * 512 + p0 + k0 + lk);
        St[lk + 0][li] = u.x; St[lk + 1][li] = u.y;
        St[lk + 2][li] = u.z; St[lk + 3][li] = u.w;
        *(float4*)&Wt[wk][wq] = *(const float4*)(WT + (size_t)(k0 + wk) * 64 + wq);
        __syncthreads();
        MICRO(St, Wt);
        __syncthreads();
    }
#pragma unroll
    for (int a = 0; a < 4; ++a) {
        const int r = i0 + (ty << 2) + a;
        *(float4*)(A + (size_t)r * 512 + p0 + (tx << 2)) =
            make_float4(acc[a][0], acc[a][1], acc[a][2], acc[a][3]);
    }
}

// Trailing update (unchanged): A[ti,tj] -= L[ti,k] L[tj,k]^T
__global__ __launch_bounds__(256)
void chol_trailing_kernel(float* __restrict__ Aall, int k)
{
    __shared__ float Ut[BK][BM + 4];
    __shared__ float Vt[BK][BN + 4];
    float* A = Aall + (size_t)blockIdx.y * 512 * 512;
    const int tid = threadIdx.x;
    int a = 0, rem = (int)blockIdx.x;
    while (rem >= a + 1) { rem -= a + 1; ++a; }
    const int ti = k + 1 + a, tj = k + 1 + rem;
    const int i0 = ti * 64, j0c = tj * 64, p0 = k * 64;

    const int li = tid >> 2, lk = (tid & 3) << 2;
    const int ty = tid >> 4, tx = tid & 15;
    float acc[4][4] = {};

    for (int k0 = 0; k0 < 64; k0 += BK) {
        const float4 u = *(const float4*)(A + (size_t)(i0 + li) * 512 + p0 + k0 + lk);
        const float4 v = *(const float4*)(A + (size_t)(j0c + li) * 512 + p0 + k0 + lk);
        Ut[lk + 0][li] = u.x; Ut[lk + 1][li] = u.y;
        Ut[lk + 2][li] = u.z; Ut[lk + 3][li] = u.w;
        Vt[lk + 0][li] = v.x; Vt[lk + 1][li] = v.y;
        Vt[lk + 2][li] = v.z; Vt[lk + 3][li] = v.w;
        __syncthreads();
        MICRO(Ut, Vt);
        __syncthreads();
    }
#pragma unroll
    for (int aa = 0; aa < 4; ++aa) {
        const int r = i0 + (ty << 2) + aa;
        float* crow = A + (size_t)r * 512 + j0c + (tx << 2);
        float4 cv = *(const float4*)crow;
        cv.x -= acc[aa][0]; cv.y -= acc[aa][1];
        cv.z -= acc[aa][2]; cv.w -= acc[aa][3];
        *(float4*)crow = cv;
    }
}

// Blocked fwd+bwd solve via diag-block inverses (unchanged from R4/R5).
__global__ __launch_bounds__(256)
void fb_solve2_kernel(const float* __restrict__ Aall,
                      const float* __restrict__ Winv,
                      const float* __restrict__ WinvT,
                      const float* __restrict__ Y, float* __restrict__ Zall)
{
    __shared__ float V[512][64];
    __shared__ float St[BK][68];
    __shared__ float Wt[BK][68];
    __shared__ float Ush[64][68];
    const int b   = blockIdx.x, tid = threadIdx.x;
    const float* A   = Aall + (size_t)b * 512 * 512;
    const float* Yb  = Y    + (size_t)b * 512 * OUTd;
    float* Z         = Zall + (size_t)b * 512 * OUTd;
    const float* Wb  = Winv  + (size_t)b * 8 * 64 * 64;
    const float* WbT = WinvT + (size_t)b * 8 * 64 * 64;

    const int li = tid >> 2, lk = (tid & 3) << 2;
    const int wk = tid >> 4, wq = (tid & 15) << 2;
    const int ty = tid >> 4, tx = tid & 15;

    for (int t = tid; t < 512 * 16; t += 256) {
        const int row = t >> 4, c4 = (t & 15) << 2;
        *(float4*)&V[row][c4] = *(const float4*)(Yb + (size_t)row * 64 + c4);
    }
    __syncthreads();

    for (int k = 0; k < 8; ++k) {
        const int r0 = k * 64;
        float acc[4][4] = {};
        for (int k0 = 0; k0 < r0; k0 += BK) {
            const float4 u = *(const float4*)(A + (size_t)(r0 + li) * 512 + k0 + lk);
            St[lk + 0][li] = u.x; St[lk + 1][li] = u.y;
            St[lk + 2][li] = u.z; St[lk + 3][li] = u.w;
            __syncthreads();
            MICRO(St, (V + k0));
            __syncthreads();
        }
#pragma unroll
        for (int a = 0; a < 4; ++a)
#pragma unroll
            for (int c = 0; c < 4; ++c)
                Ush[(ty << 2) + a][(tx << 2) + c] =
                    V[r0 + (ty << 2) + a][(tx << 2) + c] - acc[a][c];
        __syncthreads();
        float acc2[4][4] = {};
        const float* WTk = WbT + (size_t)k * 64 * 64;
        for (int k0 = 0; k0 < 64; k0 += BK) {
            *(float4*)&Wt[wk][wq] = *(const float4*)(WTk + (size_t)(k0 + wk) * 64 + wq);
            __syncthreads();
            {
                float (*acc)[4] = acc2;
                MICRO(Wt, (Ush + k0));
            }
            __syncthreads();
        }
#pragma unroll
        for (int a = 0; a < 4; ++a)
#pragma unroll
            for (int c = 0; c < 4; ++c)
                V[r0 + (ty << 2) + a][(tx << 2) + c] = acc2[a][c];
        __syncthreads();
    }

    for (int k = 7; k >= 0; --k) {
        const int r0 = k * 64;
        float acc[4][4] = {};
        for (int m0 = r0 + 64; m0 < 512; m0 += BK) {
            *(float4*)&St[wk][wq] = *(const float4*)(A + (size_t)(m0 + wk) * 512 + r0 + wq);
            __syncthreads();
            MICRO(St, (V + m0));
            __syncthreads();
        }
#pragma unroll
        for (int a = 0; a < 4; ++a)
#pragma unroll
            for (int c = 0; c < 4; ++c)
                Ush[(ty << 2) + a][(tx << 2) + c] =
                    V[r0 + (ty << 2) + a][(tx << 2) + c] - acc[a][c];
        __syncthreads();
        float acc2[4][4] = {};
        const float* Wk = Wb + (size_t)k * 64 * 64;
        for (int k0 = 0; k0 < 64; k0 += BK) {
            *(float4*)&Wt[wk][wq] = *(const float4*)(Wk + (size_t)(k0 + wk) * 64 + wq);
            __syncthreads();
            {
                float (*acc)[4] = acc2;
                MICRO(Wt, (Ush + k0));
            }
            __syncthreads();
        }
#pragma unroll
        for (int a = 0; a < 4; ++a)
#pragma unroll
            for (int c = 0; c < 4; ++c)
                V[r0 + (ty << 2) + a][(tx << 2) + c] = acc2[a][c];
        __syncthreads();
    }

    for (int t = tid; t < 512 * 16; t += 256) {
        const int row = t >> 4, c4 = (t & 15) << 2;
        *(float4*)(Z + (size_t)row * 64 + c4) = *(const float4*)&V[row][c4];
    }
}

// w[b] = RS_b^T @ Z_b, RS reconstructed as h+l.
__global__ __launch_bounds__(256)
void out_kernel(const u16* __restrict__ Sh, const u16* __restrict__ Sl,
                const float* __restrict__ Z, float* __restrict__ Wout)
{
    __shared__ float Rt[BK][64 + 4];
    __shared__ float Zt[BK][64 + 4];
    const int tid = threadIdx.x;
    const int b   = blockIdx.y;
    const int d0  = blockIdx.x * 64;
    const int kk  = tid >> 4, cq = (tid & 15) << 2;
    const int ty  = tid >> 4, tx = tid & 15;
    float acc[4][4] = {};

    for (int k0 = 0; k0 < Tt; k0 += BK) {
        const size_t ri = (size_t)(b * Tt + k0 + kk) * RES + d0 + cq;
        const u16x4 hv = *(const u16x4*)&Sh[ri];
        const u16x4 lv = *(const u16x4*)&Sl[ri];
        Rt[kk][cq + 0] = bf2f(hv[0]) + bf2f(lv[0]);
        Rt[kk][cq + 1] = bf2f(hv[1]) + bf2f(lv[1]);
        Rt[kk][cq + 2] = bf2f(hv[2]) + bf2f(lv[2]);
        Rt[kk][cq + 3] = bf2f(hv[3]) + bf2f(lv[3]);
        *(float4*)&Zt[kk][cq] =
            *(const float4*)(Z + ((size_t)b * Tt + k0 + kk) * OUTd + cq);
        __syncthreads();
        MICRO(Rt, Zt);
        __syncthreads();
    }
#pragma unroll
    for (int a = 0; a < 4; ++a) {
        const int d = d0 + (ty << 2) + a;
        *(float4*)(Wout + ((size_t)b * RES + d) * OUTd + (tx << 2)) =
            make_float4(acc[a][0], acc[a][1], acc[a][2], acc[a][3]);
    }
}

__global__ __launch_bounds__(64)
void bias_kernel(const float* __restrict__ Z, float* __restrict__ Bout)
{
    const int b = blockIdx.x, o = threadIdx.x;
    const float* Zb = Z + (size_t)b * Tt * OUTd;
    float s = 0.f;
    for (int n = 0; n < Tt; ++n) s += Zb[(size_t)n * OUTd + o];
    Bout[(size_t)b * OUTd + o] = s;
}

extern "C" void kernel_launch(void* const* d_in, const int* in_sizes, int n_in,
                              void* d_out, int out_size, void* d_ws, size_t ws_size,
                              hipStream_t stream)
{
    const float* X    = (const float*)d_in[0];   // (32,512,128)
    const float* Y    = (const float*)d_in[1];   // (32,512,64)
    const float* Wres = (const float*)d_in[2];   // (2048,2048)
    const float* Win  = (const float*)d_in[3];   // (128,2048)
    const float* lam  = (const float*)d_in[4];   // scalar

    float* out  = (float*)d_out;
    float* Wout = out;
    float* Bout = out + (size_t)Bb * RES * OUTd;

    // ws: Sh 64 | Sl 64 | WTh 8 | WTl 8 | WinTh .5 | WinTl .5 | A 32 | Z 4 | Wi 4 | WiT 4 = 189 MB
    char* p = (char*)d_ws;
    u16* Sh    = (u16*)p;   p += (size_t)Bb * Tt * RES * 2;
    u16* Sl    = (u16*)p;   p += (size_t)Bb * Tt * RES * 2;
    u16* WTh   = (u16*)p;   p += (size_t)RES * RES * 2;
    u16* WTl   = (u16*)p;   p += (size_t)RES * RES * 2;
    u16* WinTh = (u16*)p;   p += (size_t)INd * RES * 2;
    u16* WinTl = (u16*)p;   p += (size_t)INd * RES * 2;
    float* A   = (float*)p; p += (size_t)Bb * 512 * 512 * 4;
    float* Z   = (float*)p; p += (size_t)Bb * Tt * OUTd * 4;
    float* Wi  = (float*)p; p += (size_t)Bb * 8 * 64 * 64 * 4;
    float* WiT = (float*)p;

    const dim3 blk(256);
    tconv_kernel<<<dim3(RES / 64, RES / 64), blk, 0, stream>>>(Wres, WTh, WTl, RES, RES);
    tconv_kernel<<<dim3(RES / 64, INd / 64), blk, 0, stream>>>(Win, WinTh, WinTl, INd, RES);

    // classes: s:(cin->cout) 0:(-,2) 1:(2,1) 2:(1,0) 3:(0,1) 4:(1,2) 5:(2,3)
    step_mfma_kernel<<<dim3(512), blk, 0, stream>>>(Sh, Sl, X, WTh, WTl, WinTh, WinTl, 0, 2, 0);
    step_mfma_kernel<<<dim3(512), blk, 0, stream>>>(Sh, Sl, X, WTh, WTl, WinTh, WinTl, 2, 1, 1);
    step_mfma_kernel<<<dim3(512), blk, 0, stream>>>(Sh, Sl, X, WTh, WTl, WinTh, WinTl, 1, 0, 2);
    step_mfma_kernel<<<dim3(512), blk, 0, stream>>>(Sh, Sl, X, WTh, WTl, WinTh, WinTl, 0, 1, 3);
    step_mfma_kernel<<<dim3(512), blk, 0, stream>>>(Sh, Sl, X, WTh, WTl, WinTh, WinTl, 1, 2, 4);
    step_mfma_kernel<<<dim3(512), blk, 0, stream>>>(Sh, Sl, X, WTh, WTl, WinTh, WinTl, 2, 3, 5);

    gram_mfma_kernel<<<dim3(10, Bb), blk, 0, stream>>>(Sh, Sl, A, lam);

    for (int k = 0; k < 8; ++k) {
        chol_diag_inv_kernel<<<dim3(Bb), dim3(64), 0, stream>>>(A, Wi, WiT, k);
        if (k < 7) {
            trsm_kernel<<<dim3(7 - k, Bb), blk, 0, stream>>>(A, WiT, k);
            const int m = 7 - k;
            chol_trailing_kernel<<<dim3(m * (m + 1) / 2, Bb), blk, 0, stream>>>(A, k);
        }
    }
    fb_solve2_kernel<<<dim3(Bb), blk, 0, stream>>>(A, Wi, WiT, Y, Z);

    out_kernel<<<dim3(RES / 64, Bb), blk, 0, stream>>>(Sh, Sl, Z, Wout);
    bias_kernel<<<dim3(Bb), dim3(OUTd), 0, stream>>>(Z, Bout);
}

// Round 7
// 2847.249 us; speedup vs baseline: 1.6292x; 1.6292x over previous
//
#include <hip/hip_runtime.h>
#include <cmath>

#define Bb   32
#define Tt   512
#define INd  128
#define RES  2048
#define OUTd 64

#define BM 64
#define BN 64
#define BK 16

typedef unsigned short u16;
typedef __attribute__((ext_vector_type(4))) unsigned short u16x4;
typedef __attribute__((ext_vector_type(8))) unsigned short u16x8;
typedef __attribute__((ext_vector_type(8))) short bf8;
typedef __attribute__((ext_vector_type(4))) float f32x4;

// fp32 = bf16 hi (RNE) + bf16 lo (trunc residual); |err| <= 2^-17 |a|
__device__ __forceinline__ void splitf(float a, u16& h, u16& l) {
    unsigned u = __float_as_uint(a);
    unsigned r = (u + 0x7fffu + ((u >> 16) & 1u)) & 0xffff0000u;
    h = (u16)(r >> 16);
    float d = a - __uint_as_float(r);
    l = (u16)(__float_as_uint(d) >> 16);
}
__device__ __forceinline__ float bf2f(u16 h) {
    return __uint_as_float((unsigned)h << 16);
}
__device__ __forceinline__ void split8(const float4& a, const float4& b,
                                       u16x8& h, u16x8& l) {
    u16 hh, ll;
    splitf(a.x, hh, ll); h[0] = hh; l[0] = ll;
    splitf(a.y, hh, ll); h[1] = hh; l[1] = ll;
    splitf(a.z, hh, ll); h[2] = hh; l[2] = ll;
    splitf(a.w, hh, ll); h[3] = hh; l[3] = ll;
    splitf(b.x, hh, ll); h[4] = hh; l[4] = ll;
    splitf(b.y, hh, ll); h[5] = hh; l[5] = ll;
    splitf(b.z, hh, ll); h[6] = hh; l[6] = ll;
    splitf(b.w, hh, ll); h[7] = hh; l[7] = ll;
}

#define MICRO(SA, SB)                                                           \
  do {                                                                          \
    _Pragma("unroll")                                                           \
    for (int kk = 0; kk < BK; ++kk) {                                           \
      const float4 a4 = *(const float4*)&SA[kk][ty << 2];                       \
      const float4 b4 = *(const float4*)&SB[kk][tx << 2];                       \
      acc[0][0] += a4.x*b4.x; acc[0][1] += a4.x*b4.y;                           \
      acc[0][2] += a4.x*b4.z; acc[0][3] += a4.x*b4.w;                           \
      acc[1][0] += a4.y*b4.x; acc[1][1] += a4.y*b4.y;                           \
      acc[1][2] += a4.y*b4.z; acc[1][3] += a4.y*b4.w;                           \
      acc[2][0] += a4.z*b4.x; acc[2][1] += a4.z*b4.y;                           \
      acc[2][2] += a4.z*b4.z; acc[2][3] += a4.z*b4.w;                           \
      acc[3][0] += a4.w*b4.x; acc[3][1] += a4.w*b4.y;                           \
      acc[3][2] += a4.w*b4.z; acc[3][3] += a4.w*b4.w;                           \
    }                                                                           \
  } while (0)

// 128x128 tile, K=32 slice, bf16x3. LDS row stride 40 u16.
#define MFMA_TILE()                                                              \
  do {                                                                           \
    bf8 aH[4], aL[4], bH[4], bL[4];                                              \
    _Pragma("unroll")                                                            \
    for (int i = 0; i < 4; ++i) {                                                \
      const int ar = (wm*64 + i*16 + l15)*40 + quad*8;                           \
      aH[i] = *(const bf8*)&Ah[ar]; aL[i] = *(const bf8*)&Al[ar];                \
      const int br = (wn*64 + i*16 + l15)*40 + quad*8;                           \
      bH[i] = *(const bf8*)&Bh[br]; bL[i] = *(const bf8*)&Bl[br];                \
    }                                                                            \
    _Pragma("unroll")                                                            \
    for (int i = 0; i < 4; ++i)                                                  \
      _Pragma("unroll")                                                          \
      for (int j = 0; j < 4; ++j) {                                              \
        acc[i][j] = __builtin_amdgcn_mfma_f32_16x16x32_bf16(aH[i], bH[j], acc[i][j], 0, 0, 0); \
        acc[i][j] = __builtin_amdgcn_mfma_f32_16x16x32_bf16(aH[i], bL[j], acc[i][j], 0, 0, 0); \
        acc[i][j] = __builtin_amdgcn_mfma_f32_16x16x32_bf16(aL[i], bH[j], acc[i][j], 0, 0, 0); \
      }                                                                          \
  } while (0)

// Transpose + split weights: in (K x N fp32) -> outH/outL (N x K bf16).
__global__ __launch_bounds__(256)
void tconv_kernel(const float* __restrict__ in, u16* __restrict__ outH,
                  u16* __restrict__ outL, int K, int N)
{
    __shared__ float T[64][65];
    const int n0 = blockIdx.x * 64, k0 = blockIdx.y * 64;
    const int t = threadIdx.x;
    const int r = t >> 2, c0 = (t & 3) * 16;
#pragma unroll
    for (int i = 0; i < 4; ++i) {
        const float4 v = *(const float4*)&in[(size_t)(k0 + r) * N + n0 + c0 + 4*i];
        T[r][c0 + 4*i + 0] = v.x; T[r][c0 + 4*i + 1] = v.y;
        T[r][c0 + 4*i + 2] = v.z; T[r][c0 + 4*i + 3] = v.w;
    }
    __syncthreads();
    const int n = t >> 2, ck = (t & 3) * 16;
    u16x8 h0, h1, l0, l1;
#pragma unroll
    for (int i = 0; i < 8; ++i) { u16 h, l; splitf(T[ck + i][n], h, l); h0[i] = h; l0[i] = l; }
#pragma unroll
    for (int i = 0; i < 8; ++i) { u16 h, l; splitf(T[ck + 8 + i][n], h, l); h1[i] = h; l1[i] = l; }
    const size_t ob = (size_t)(n0 + n) * K + k0 + ck;
    *(u16x8*)&outH[ob] = h0; *(u16x8*)&outH[ob + 8] = h1;
    *(u16x8*)&outL[ob] = l0; *(u16x8*)&outL[ob + 8] = l1;
}

// Reservoir step on bf16 hi/lo state planes (row = b*512 + 4w + class).
// Epilogue goes through LDS so every global store is a coalesced u16x8.
__global__ __launch_bounds__(256)
void step_mfma_kernel(u16* __restrict__ Sh, u16* __restrict__ Sl,
                      const float* __restrict__ X,
                      const u16* __restrict__ WTh, const u16* __restrict__ WTl,
                      const u16* __restrict__ WinTh, const u16* __restrict__ WinTl,
                      int cin, int cout, int s)
{
    __shared__ u16 LB[4 * 128 * 40];          // 40 KB, aliased below
    u16* Ah = LB;
    u16* Al = LB + 5120;
    u16* Bh = LB + 10240;
    u16* Bl = LB + 15360;
    float* Cf = (float*)LB;                   // 64x128 f32 = 32 KB (epilogue)

    const int tid = threadIdx.x;
    const int q0  = blockIdx.x * 128;         // reservoir-col tile
    const int b   = blockIdx.y;
    const int bofs = b * Tt;
    const int wid = tid >> 6, lane = tid & 63;
    const int wm = wid & 1, wn = wid >> 1;
    const int l15 = lane & 15, quad = lane >> 4;
    const int row  = tid & 127;               // staging row within 128-tile
    const int pick = tid >> 7;                // 0: A-operand (state), 1: B (W)

    f32x4 acc[4][4];
    const f32x4 zz = {0.f, 0.f, 0.f, 0.f};
#pragma unroll
    for (int i = 0; i < 4; ++i)
#pragma unroll
        for (int j = 0; j < 4; ++j) acc[i][j] = zz;

    u16* dH = (pick ? Bh : Ah) + row * 40;
    u16* dL = (pick ? Bl : Al) + row * 40;

    if (s > 0) {
        const size_t gr = pick ? (size_t)(q0 + row) * RES
                               : (size_t)(bofs + 4 * row + cin) * RES;
        const u16* gH = (pick ? WTh : Sh) + gr;
        const u16* gL = (pick ? WTl : Sl) + gr;
        for (int k0 = 0; k0 < RES; k0 += 32) {
            *(u16x8*)&dH[0]  = *(const u16x8*)&gH[k0 + 0];
            *(u16x8*)&dH[8]  = *(const u16x8*)&gH[k0 + 8];
            *(u16x8*)&dH[16] = *(const u16x8*)&gH[k0 + 16];
            *(u16x8*)&dH[24] = *(const u16x8*)&gH[k0 + 24];
            *(u16x8*)&dL[0]  = *(const u16x8*)&gL[k0 + 0];
            *(u16x8*)&dL[8]  = *(const u16x8*)&gL[k0 + 8];
            *(u16x8*)&dL[16] = *(const u16x8*)&gL[k0 + 16];
            *(u16x8*)&dL[24] = *(const u16x8*)&gL[k0 + 24];
            __syncthreads();
            MFMA_TILE();
            __syncthreads();
        }
    }

    // input projection: K=128 over x[b, 4w+s-2, :] @ Win
    for (int k0 = 0; k0 < INd; k0 += 32) {
        if (pick == 0) {
            const int t = 4 * row + s - 2;
            u16x8 h0 = {0,0,0,0,0,0,0,0}, h1 = h0, h2 = h0, h3 = h0;
            u16x8 l0 = h0, l1 = h0, l2 = h0, l3 = h0;
            if (t >= 0) {
                const float* xr = X + (size_t)(bofs + t) * INd + k0;
                const float4 f0 = *(const float4*)&xr[0];
                const float4 f1 = *(const float4*)&xr[4];
                const float4 f2 = *(const float4*)&xr[8];
                const float4 f3 = *(const float4*)&xr[12];
                const float4 f4 = *(const float4*)&xr[16];
                const float4 f5 = *(const float4*)&xr[20];
                const float4 f6 = *(const float4*)&xr[24];
                const float4 f7 = *(const float4*)&xr[28];
                split8(f0, f1, h0, l0); split8(f2, f3, h1, l1);
                split8(f4, f5, h2, l2); split8(f6, f7, h3, l3);
            }
            *(u16x8*)&dH[0] = h0;  *(u16x8*)&dH[8] = h1;
            *(u16x8*)&dH[16] = h2; *(u16x8*)&dH[24] = h3;
            *(u16x8*)&dL[0] = l0;  *(u16x8*)&dL[8] = l1;
            *(u16x8*)&dL[16] = l2; *(u16x8*)&dL[24] = l3;
        } else {
            const size_t gr = (size_t)(q0 + row) * INd + k0;
            *(u16x8*)&dH[0]  = *(const u16x8*)&WinTh[gr];
            *(u16x8*)&dH[8]  = *(const u16x8*)&WinTh[gr + 8];
            *(u16x8*)&dH[16] = *(const u16x8*)&WinTh[gr + 16];
            *(u16x8*)&dH[24] = *(const u16x8*)&WinTh[gr + 24];
            *(u16x8*)&dL[0]  = *(const u16x8*)&WinTl[gr];
            *(u16x8*)&dL[8]  = *(const u16x8*)&WinTl[gr + 8];
            *(u16x8*)&dL[16] = *(const u16x8*)&WinTl[gr + 16];
            *(u16x8*)&dL[24] = *(const u16x8*)&WinTl[gr + 24];
        }
        __syncthreads();
        MFMA_TILE();
        __syncthreads();
    }

    // epilogue via LDS: half h covers w-rows h*64..h*64+63; all global I/O
    // is u16x8 (16B/lane, 256B contiguous per 16 lanes).
    for (int h = 0; h < 2; ++h) {
        __syncthreads();
        if (wm == h) {
#pragma unroll
            for (int i = 0; i < 4; ++i)
#pragma unroll
                for (int j = 0; j < 4; ++j)
#pragma unroll
                    for (int rg = 0; rg < 4; ++rg)
                        Cf[(i * 16 + quad * 4 + rg) * 128 + wn * 64 + j * 16 + l15]
                            = acc[i][j][rg];
        }
        __syncthreads();
#pragma unroll
        for (int pass = 0; pass < 4; ++pass) {
            const int r  = (tid >> 4) + pass * 16;      // 0..63
            const int c0 = (tid & 15) * 8;              // 0..120
            const int wrow = h * 64 + r;
            const float4 v0 = *(const float4*)&Cf[r * 128 + c0];
            const float4 v1 = *(const float4*)&Cf[r * 128 + c0 + 4];
            float vv[8] = {v0.x, v0.y, v0.z, v0.w, v1.x, v1.y, v1.z, v1.w};
            u16x8 ph, pl;
            if (s > 0) {
                const size_t prow = (size_t)(bofs + 4 * wrow + cin) * RES + q0 + c0;
                ph = *(const u16x8*)&Sh[prow];
                pl = *(const u16x8*)&Sl[prow];
            }
            u16x8 oh, ol;
#pragma unroll
            for (int e = 0; e < 8; ++e) {
                float prev = (s > 0) ? (bf2f(ph[e]) + bf2f(pl[e])) : 0.f;
                float v = 0.7f * prev + 0.3f * sinf(vv[e]);
                u16 hh, ll; splitf(v, hh, ll);
                oh[e] = hh; ol[e] = ll;
            }
            const size_t orow = (size_t)(bofs + 4 * wrow + cout) * RES + q0 + c0;
            *(u16x8*)&Sh[orow] = oh;
            *(u16x8*)&Sl[orow] = ol;
        }
    }
}

// Gram on bf16 planes: A[b] = (Sh+Sl)(Sh+Sl)^T + ones + reg*I, bf16x3.
// Epilogue via LDS (stride 132) -> coalesced float4 stores, both orientations.
__global__ __launch_bounds__(256)
void gram_mfma_kernel(const u16* __restrict__ Sh, const u16* __restrict__ Sl,
                      float* __restrict__ A, const float* __restrict__ lam)
{
    __shared__ u16 LB[4 * 128 * 40];
    u16* Ah = LB;
    u16* Al = LB + 5120;
    u16* Bh = LB + 10240;
    u16* Bl = LB + 15360;
    float* Cf = (float*)LB;                   // 64 x 132 f32 = 33.8 KB

    const int tid = threadIdx.x;
    const int bt  = blockIdx.y;
    int ti = 0, rem = (int)blockIdx.x;
    while (rem >= 4 - ti) { rem -= 4 - ti; ++ti; }
    const int tj = ti + rem;
    const int n0 = ti * 128, m0 = tj * 128;
    const int bofs = bt * Tt;

    const int wid = tid >> 6, lane = tid & 63;
    const int wm = wid & 1, wn = wid >> 1;
    const int l15 = lane & 15, quad = lane >> 4;
    const int row  = tid & 127;
    const int pick = tid >> 7;

    f32x4 acc[4][4];
    const f32x4 zz = {0.f, 0.f, 0.f, 0.f};
#pragma unroll
    for (int i = 0; i < 4; ++i)
#pragma unroll
        for (int j = 0; j < 4; ++j) acc[i][j] = zz;

    u16* dH = (pick ? Bh : Ah) + row * 40;
    u16* dL = (pick ? Bl : Al) + row * 40;
    const size_t gr = (size_t)(bofs + (pick ? m0 : n0) + row) * RES;
    const u16* gH = Sh + gr;
    const u16* gL = Sl + gr;

    for (int k0 = 0; k0 < RES; k0 += 32) {
        *(u16x8*)&dH[0]  = *(const u16x8*)&gH[k0 + 0];
        *(u16x8*)&dH[8]  = *(const u16x8*)&gH[k0 + 8];
        *(u16x8*)&dH[16] = *(const u16x8*)&gH[k0 + 16];
        *(u16x8*)&dH[24] = *(const u16x8*)&gH[k0 + 24];
        *(u16x8*)&dL[0]  = *(const u16x8*)&gL[k0 + 0];
        *(u16x8*)&dL[8]  = *(const u16x8*)&gL[k0 + 8];
        *(u16x8*)&dL[16] = *(const u16x8*)&gL[k0 + 16];
        *(u16x8*)&dL[24] = *(const u16x8*)&gL[k0 + 24];
        __syncthreads();
        MFMA_TILE();
        __syncthreads();
    }

    const float reg = log1pf(expf(lam[0]));
    float* Ab = A + (size_t)bt * 512 * 512;
    for (int h = 0; h < 2; ++h) {
        __syncthreads();
        if (wm == h) {
#pragma unroll
            for (int i = 0; i < 4; ++i)
#pragma unroll
                for (int j = 0; j < 4; ++j)
#pragma unroll
                    for (int rg = 0; rg < 4; ++rg)
                        Cf[(i * 16 + quad * 4 + rg) * 132 + wn * 64 + j * 16 + l15]
                            = acc[i][j][rg];
        }
        __syncthreads();
        // row-major half: rows nn = n0+h*64+r, cols m0..m0+127
#pragma unroll
        for (int pass = 0; pass < 4; ++pass) {
            const int r  = (tid >> 4) + pass * 16;
            const int c0 = (tid & 15) * 8;
            const int nn = n0 + h * 64 + r;
            float o[8];
#pragma unroll
            for (int e = 0; e < 8; ++e) {
                const int mm = m0 + c0 + e;
                float v = Cf[r * 132 + c0 + e] + 1.0f;
                if (nn == mm) v += reg;
                o[e] = v;
            }
            float* dst = Ab + (size_t)nn * 512 + m0 + c0;
            *(float4*)&dst[0] = make_float4(o[0], o[1], o[2], o[3]);
            *(float4*)&dst[4] = make_float4(o[4], o[5], o[6], o[7]);
        }
        // transposed half: rows mm = m0+rt, cols n0+h*64 .. +63
#pragma unroll
        for (int pass = 0; pass < 4; ++pass) {
            const int rt  = (tid >> 3) + pass * 32;     // 0..127
            const int c0t = (tid & 7) * 8;              // 0..56
            const int mm  = m0 + rt;
            float o[8];
#pragma unroll
            for (int e = 0; e < 8; ++e) {
                const int nn = n0 + h * 64 + c0t + e;
                float v = Cf[(c0t + e) * 132 + rt] + 1.0f;
                if (nn == mm) v += reg;
                o[e] = v;
            }
            float* dst = Ab + (size_t)mm * 512 + n0 + h * 64 + c0t;
            *(float4*)&dst[0] = make_float4(o[0], o[1], o[2], o[3]);
            *(float4*)&dst[4] = make_float4(o[4], o[5], o[6], o[7]);
        }
    }
}

// Diag-block Cholesky (64x64) + inverse, one wave per batch.
__global__ __launch_bounds__(64)
void chol_diag_inv_kernel(float* __restrict__ Aall, float* __restrict__ Winv,
                          float* __restrict__ WinvT, int k)
{
    __shared__ float P[64][65];
    __shared__ float W[64][65];
    const int b = blockIdx.x, c = threadIdx.x;
    float* A = Aall + (size_t)b * 512 * 512;
    const int j0 = 64 * k;

    for (int m = 0; m < 64; m += 4) {
        const float4 v = *(const float4*)(A + (size_t)(j0 + c) * 512 + j0 + m);
        P[c][m] = v.x; P[c][m+1] = v.y; P[c][m+2] = v.z; P[c][m+3] = v.w;
    }
    __syncthreads();
    for (int j = 0; j < 64; ++j) {
        const float d = sqrtf(P[j][j]);
        if (c >= j) P[c][j] = (c == j) ? d : P[c][j] / d;
        __syncthreads();
        const float pj = (c > j) ? P[c][j] : 0.f;
        for (int m = j + 1; m <= c; ++m) P[c][m] -= pj * P[m][j];
        __syncthreads();
    }
    for (int j = 0; j < 64; ++j) {
        float sv = (j == c) ? 1.f : 0.f;
        for (int m = c; m < j; ++m) sv -= P[j][m] * W[m][c];
        W[j][c] = (j >= c) ? sv / P[j][j] : 0.f;
    }
    __syncthreads();
    for (int m = 0; m < 64; m += 4)
        *(float4*)(A + (size_t)(j0 + c) * 512 + j0 + m) =
            make_float4(P[c][m], P[c][m+1], P[c][m+2], P[c][m+3]);
    float* Wo  = Winv  + ((size_t)b * 8 + k) * 64 * 64;
    float* WoT = WinvT + ((size_t)b * 8 + k) * 64 * 64;
    for (int j = 0; j < 64; ++j) Wo[(size_t)j * 64 + c] = W[j][c];
    for (int m = 0; m < 64; m += 4)
        *(float4*)(WoT + (size_t)c * 64 + m) =
            make_float4(W[m][c], W[m+1][c], W[m+2][c], W[m+3][c]);
}

// Panel TRSM via inverse: L[i0.., k] = A[i0.., k] @ W^T
__global__ __launch_bounds__(256)
void trsm_kernel(float* __restrict__ Aall, const float* __restrict__ WinvT, int k)
{
    __shared__ float St[BK][BM + 4];
    __shared__ float Wt[BK][BN + 4];
    float* A = Aall + (size_t)blockIdx.y * 512 * 512;
    const float* WT = WinvT + ((size_t)blockIdx.y * 8 + k) * 64 * 64;
    const int i0 = (k + 1 + blockIdx.x) * 64, p0 = k * 64;
    const int tid = threadIdx.x;
    const int li = tid >> 2, lk = (tid & 3) << 2;
    const int wk = tid >> 4, wq = (tid & 15) << 2;
    const int ty = tid >> 4, tx = tid & 15;
    float acc[4][4] = {};
    for (int k0 = 0; k0 < 64; k0 += BK) {
        const float4 u = *(const float4*)(A + (size_t)(i0 + li) * 512 + p0 + k0 + lk);
        St[lk + 0][li] = u.x; St[lk + 1][li] = u.y;
        St[lk + 2][li] = u.z; St[lk + 3][li] = u.w;
        *(float4*)&Wt[wk][wq] = *(const float4*)(WT + (size_t)(k0 + wk) * 64 + wq);
        __syncthreads();
        MICRO(St, Wt);
        __syncthreads();
    }
#pragma unroll
    for (int a = 0; a < 4; ++a) {
        const int r = i0 + (ty << 2) + a;
        *(float4*)(A + (size_t)r * 512 + p0 + (tx << 2)) =
            make_float4(acc[a][0], acc[a][1], acc[a][2], acc[a][3]);
    }
}

// Trailing update: A[ti,tj] -= L[ti,k] L[tj,k]^T
__global__ __launch_bounds__(256)
void chol_trailing_kernel(float* __restrict__ Aall, int k)
{
    __shared__ float Ut[BK][BM + 4];
    __shared__ float Vt[BK][BN + 4];
    float* A = Aall + (size_t)blockIdx.y * 512 * 512;
    const int tid = threadIdx.x;
    int a = 0, rem = (int)blockIdx.x;
    while (rem >= a + 1) { rem -= a + 1; ++a; }
    const int ti = k + 1 + a, tj = k + 1 + rem;
    const int i0 = ti * 64, j0c = tj * 64, p0 = k * 64;

    const int li = tid >> 2, lk = (tid & 3) << 2;
    const int ty = tid >> 4, tx = tid & 15;
    float acc[4][4] = {};

    for (int k0 = 0; k0 < 64; k0 += BK) {
        const float4 u = *(const float4*)(A + (size_t)(i0 + li) * 512 + p0 + k0 + lk);
        const float4 v = *(const float4*)(A + (size_t)(j0c + li) * 512 + p0 + k0 + lk);
        Ut[lk + 0][li] = u.x; Ut[lk + 1][li] = u.y;
        Ut[lk + 2][li] = u.z; Ut[lk + 3][li] = u.w;
        Vt[lk + 0][li] = v.x; Vt[lk + 1][li] = v.y;
        Vt[lk + 2][li] = v.z; Vt[lk + 3][li] = v.w;
        __syncthreads();
        MICRO(Ut, Vt);
        __syncthreads();
    }
#pragma unroll
    for (int aa = 0; aa < 4; ++aa) {
        const int r = i0 + (ty << 2) + aa;
        float* crow = A + (size_t)r * 512 + j0c + (tx << 2);
        float4 cv = *(const float4*)crow;
        cv.x -= acc[aa][0]; cv.y -= acc[aa][1];
        cv.z -= acc[aa][2]; cv.w -= acc[aa][3];
        *(float4*)crow = cv;
    }
}

// Blocked fwd+bwd solve via diag-block inverses.
__global__ __launch_bounds__(256)
void fb_solve2_kernel(const float* __restrict__ Aall,
                      const float* __restrict__ Winv,
                      const float* __restrict__ WinvT,
                      const float* __restrict__ Y, float* __restrict__ Zall)
{
    __shared__ float V[512][64];
    __shared__ float St[BK][68];
    __shared__ float Wt[BK][68];
    __shared__ float Ush[64][68];
    const int b   = blockIdx.x, tid = threadIdx.x;
    const float* A   = Aall + (size_t)b * 512 * 512;
    const float* Yb  = Y    + (size_t)b * 512 * OUTd;
    float* Z         = Zall + (size_t)b * 512 * OUTd;
    const float* Wb  = Winv  + (size_t)b * 8 * 64 * 64;
    const float* WbT = WinvT + (size_t)b * 8 * 64 * 64;

    const int li = tid >> 2, lk = (tid & 3) << 2;
    const int wk = tid >> 4, wq = (tid & 15) << 2;
    const int ty = tid >> 4, tx = tid & 15;

    for (int t = tid; t < 512 * 16; t += 256) {
        const int row = t >> 4, c4 = (t & 15) << 2;
        *(float4*)&V[row][c4] = *(const float4*)(Yb + (size_t)row * 64 + c4);
    }
    __syncthreads();

    for (int k = 0; k < 8; ++k) {
        const int r0 = k * 64;
        float acc[4][4] = {};
        for (int k0 = 0; k0 < r0; k0 += BK) {
            const float4 u = *(const float4*)(A + (size_t)(r0 + li) * 512 + k0 + lk);
            St[lk + 0][li] = u.x; St[lk + 1][li] = u.y;
            St[lk + 2][li] = u.z; St[lk + 3][li] = u.w;
            __syncthreads();
            MICRO(St, (V + k0));
            __syncthreads();
        }
#pragma unroll
        for (int a = 0; a < 4; ++a)
#pragma unroll
            for (int c = 0; c < 4; ++c)
                Ush[(ty << 2) + a][(tx << 2) + c] =
                    V[r0 + (ty << 2) + a][(tx << 2) + c] - acc[a][c];
        __syncthreads();
        float acc2[4][4] = {};
        const float* WTk = WbT + (size_t)k * 64 * 64;
        for (int k0 = 0; k0 < 64; k0 += BK) {
            *(float4*)&Wt[wk][wq] = *(const float4*)(WTk + (size_t)(k0 + wk) * 64 + wq);
            __syncthreads();
            {
                float (*acc)[4] = acc2;
                MICRO(Wt, (Ush + k0));
            }
            __syncthreads();
        }
#pragma unroll
        for (int a = 0; a < 4; ++a)
#pragma unroll
            for (int c = 0; c < 4; ++c)
                V[r0 + (ty << 2) + a][(tx << 2) + c] = acc2[a][c];
        __syncthreads();
    }

    for (int k = 7; k >= 0; --k) {
        const int r0 = k * 64;
        float acc[4][4] = {};
        for (int m0 = r0 + 64; m0 < 512; m0 += BK) {
            *(float4*)&St[wk][wq] = *(const float4*)(A + (size_t)(m0 + wk) * 512 + r0 + wq);
            __syncthreads();
            MICRO(St, (V + m0));
            __syncthreads();
        }
#pragma unroll
        for (int a = 0; a < 4; ++a)
#pragma unroll
            for (int c = 0; c < 4; ++c)
                Ush[(ty << 2) + a][(tx << 2) + c] =
                    V[r0 + (ty << 2) + a][(tx << 2) + c] - acc[a][c];
        __syncthreads();
        float acc2[4][4] = {};
        const float* Wk = Wb + (size_t)k * 64 * 64;
        for (int k0 = 0; k0 < 64; k0 += BK) {
            *(float4*)&Wt[wk][wq] = *(const float4*)(Wk + (size_t)(k0 + wk) * 64 + wq);
            __syncthreads();
            {
                float (*acc)[4] = acc2;
                MICRO(Wt, (Ush + k0));
            }
            __syncthreads();
        }
#pragma unroll
        for (int a = 0; a < 4; ++a)
#pragma unroll
            for (int c = 0; c < 4; ++c)
                V[r0 + (ty << 2) + a][(tx << 2) + c] = acc2[a][c];
        __syncthreads();
    }

    for (int t = tid; t < 512 * 16; t += 256) {
        const int row = t >> 4, c4 = (t & 15) << 2;
        *(float4*)(Z + (size_t)row * 64 + c4) = *(const float4*)&V[row][c4];
    }
}

// w[b] = RS_b^T @ Z_b, RS reconstructed as h+l.
__global__ __launch_bounds__(256)
void out_kernel(const u16* __restrict__ Sh, const u16* __restrict__ Sl,
                const float* __restrict__ Z, float* __restrict__ Wout)
{
    __shared__ float Rt[BK][64 + 4];
    __shared__ float Zt[BK][64 + 4];
    const int tid = threadIdx.x;
    const int b   = blockIdx.y;
    const int d0  = blockIdx.x * 64;
    const int kk  = tid >> 4, cq = (tid & 15) << 2;
    const int ty  = tid >> 4, tx = tid & 15;
    float acc[4][4] = {};

    for (int k0 = 0; k0 < Tt; k0 += BK) {
        const size_t ri = (size_t)(b * Tt + k0 + kk) * RES + d0 + cq;
        const u16x4 hv = *(const u16x4*)&Sh[ri];
        const u16x4 lv = *(const u16x4*)&Sl[ri];
        Rt[kk][cq + 0] = bf2f(hv[0]) + bf2f(lv[0]);
        Rt[kk][cq + 1] = bf2f(hv[1]) + bf2f(lv[1]);
        Rt[kk][cq + 2] = bf2f(hv[2]) + bf2f(lv[2]);
        Rt[kk][cq + 3] = bf2f(hv[3]) + bf2f(lv[3]);
        *(float4*)&Zt[kk][cq] =
            *(const float4*)(Z + ((size_t)b * Tt + k0 + kk) * OUTd + cq);
        __syncthreads();
        MICRO(Rt, Zt);
        __syncthreads();
    }
#pragma unroll
    for (int a = 0; a < 4; ++a) {
        const int d = d0 + (ty << 2) + a;
        *(float4*)(Wout + ((size_t)b * RES + d) * OUTd + (tx << 2)) =
            make_float4(acc[a][0], acc[a][1], acc[a][2], acc[a][3]);
    }
}

__global__ __launch_bounds__(64)
void bias_kernel(const float* __restrict__ Z, float* __restrict__ Bout)
{
    const int b = blockIdx.x, o = threadIdx.x;
    const float* Zb = Z + (size_t)b * Tt * OUTd;
    float s = 0.f;
    for (int n = 0; n < Tt; ++n) s += Zb[(size_t)n * OUTd + o];
    Bout[(size_t)b * OUTd + o] = s;
}

extern "C" void kernel_launch(void* const* d_in, const int* in_sizes, int n_in,
                              void* d_out, int out_size, void* d_ws, size_t ws_size,
                              hipStream_t stream)
{
    const float* X    = (const float*)d_in[0];   // (32,512,128)
    const float* Y    = (const float*)d_in[1];   // (32,512,64)
    const float* Wres = (const float*)d_in[2];   // (2048,2048)
    const float* Win  = (const float*)d_in[3];   // (128,2048)
    const float* lam  = (const float*)d_in[4];   // scalar

    float* out  = (float*)d_out;
    float* Wout = out;
    float* Bout = out + (size_t)Bb * RES * OUTd;

    // ws: Sh 64 | Sl 64 | WTh 8 | WTl 8 | WinTh .5 | WinTl .5 | A 32 | Z 4 | Wi 4 | WiT 4 = 189 MB
    char* p = (char*)d_ws;
    u16* Sh    = (u16*)p;   p += (size_t)Bb * Tt * RES * 2;
    u16* Sl    = (u16*)p;   p += (size_t)Bb * Tt * RES * 2;
    u16* WTh   = (u16*)p;   p += (size_t)RES * RES * 2;
    u16* WTl   = (u16*)p;   p += (size_t)RES * RES * 2;
    u16* WinTh = (u16*)p;   p += (size_t)INd * RES * 2;
    u16* WinTl = (u16*)p;   p += (size_t)INd * RES * 2;
    float* A   = (float*)p; p += (size_t)Bb * 512 * 512 * 4;
    float* Z   = (float*)p; p += (size_t)Bb * Tt * OUTd * 4;
    float* Wi  = (float*)p; p += (size_t)Bb * 8 * 64 * 64 * 4;
    float* WiT = (float*)p;

    const dim3 blk(256);
    tconv_kernel<<<dim3(RES / 64, RES / 64), blk, 0, stream>>>(Wres, WTh, WTl, RES, RES);
    tconv_kernel<<<dim3(RES / 64, INd / 64), blk, 0, stream>>>(Win, WinTh, WinTl, INd, RES);

    // classes: s:(cin->cout) 0:(-,2) 1:(2,1) 2:(1,0) 3:(0,1) 4:(1,2) 5:(2,3)
    const dim3 sgrid(RES / 128, Bb);
    step_mfma_kernel<<<sgrid, blk, 0, stream>>>(Sh, Sl, X, WTh, WTl, WinTh, WinTl, 0, 2, 0);
    step_mfma_kernel<<<sgrid, blk, 0, stream>>>(Sh, Sl, X, WTh, WTl, WinTh, WinTl, 2, 1, 1);
    step_mfma_kernel<<<sgrid, blk, 0, stream>>>(Sh, Sl, X, WTh, WTl, WinTh, WinTl, 1, 0, 2);
    step_mfma_kernel<<<sgrid, blk, 0, stream>>>(Sh, Sl, X, WTh, WTl, WinTh, WinTl, 0, 1, 3);
    step_mfma_kernel<<<sgrid, blk, 0, stream>>>(Sh, Sl, X, WTh, WTl, WinTh, WinTl, 1, 2, 4);
    step_mfma_kernel<<<sgrid, blk, 0, stream>>>(Sh, Sl, X, WTh, WTl, WinTh, WinTl, 2, 3, 5);

    gram_mfma_kernel<<<dim3(10, Bb), blk, 0, stream>>>(Sh, Sl, A, lam);

    for (int k = 0; k < 8; ++k) {
        chol_diag_inv_kernel<<<dim3(Bb), dim3(64), 0, stream>>>(A, Wi, WiT, k);
        if (k < 7) {
            trsm_kernel<<<dim3(7 - k, Bb), blk, 0, stream>>>(A, WiT, k);
            const int m = 7 - k;
            chol_trailing_kernel<<<dim3(m * (m + 1) / 2, Bb), blk, 0, stream>>>(A, k);
        }
    }
    fb_solve2_kernel<<<dim3(Bb), blk, 0, stream>>>(A, Wi, WiT, Y, Z);

    out_kernel<<<dim3(RES / 64, Bb), blk, 0, stream>>>(Sh, Sl, Z, Wout);
    bias_kernel<<<dim3(Bb), dim3(OUTd), 0, stream>>>(Z, Bout);
}

// Round 8
// 2791.745 us; speedup vs baseline: 1.6616x; 1.0199x over previous
//
#include <hip/hip_runtime.h>
#include <cmath>

#define Bb   32
#define Tt   512
#define INd  128
#define RES  2048
#define OUTd 64

#define BM 64
#define BN 64
#define BK 16

typedef unsigned short u16;
typedef __attribute__((ext_vector_type(4))) unsigned short u16x4;
typedef __attribute__((ext_vector_type(8))) unsigned short u16x8;
typedef __attribute__((ext_vector_type(8))) short bf8;
typedef __attribute__((ext_vector_type(4))) float f32x4;

// fp32 = bf16 hi (RNE) + bf16 lo (trunc residual); |err| <= 2^-17 |a|
__device__ __forceinline__ void splitf(float a, u16& h, u16& l) {
    unsigned u = __float_as_uint(a);
    unsigned r = (u + 0x7fffu + ((u >> 16) & 1u)) & 0xffff0000u;
    h = (u16)(r >> 16);
    float d = a - __uint_as_float(r);
    l = (u16)(__float_as_uint(d) >> 16);
}
__device__ __forceinline__ float bf2f(u16 h) {
    return __uint_as_float((unsigned)h << 16);
}
__device__ __forceinline__ void split8(const float4& a, const float4& b,
                                       u16x8& h, u16x8& l) {
    u16 hh, ll;
    splitf(a.x, hh, ll); h[0] = hh; l[0] = ll;
    splitf(a.y, hh, ll); h[1] = hh; l[1] = ll;
    splitf(a.z, hh, ll); h[2] = hh; l[2] = ll;
    splitf(a.w, hh, ll); h[3] = hh; l[3] = ll;
    splitf(b.x, hh, ll); h[4] = hh; l[4] = ll;
    splitf(b.y, hh, ll); h[5] = hh; l[5] = ll;
    splitf(b.z, hh, ll); h[6] = hh; l[6] = ll;
    splitf(b.w, hh, ll); h[7] = hh; l[7] = ll;
}

#define MICRO(SA, SB)                                                           \
  do {                                                                          \
    _Pragma("unroll")                                                           \
    for (int kk = 0; kk < BK; ++kk) {                                           \
      const float4 a4 = *(const float4*)&SA[kk][ty << 2];                       \
      const float4 b4 = *(const float4*)&SB[kk][tx << 2];                       \
      acc[0][0] += a4.x*b4.x; acc[0][1] += a4.x*b4.y;                           \
      acc[0][2] += a4.x*b4.z; acc[0][3] += a4.x*b4.w;                           \
      acc[1][0] += a4.y*b4.x; acc[1][1] += a4.y*b4.y;                           \
      acc[1][2] += a4.y*b4.z; acc[1][3] += a4.y*b4.w;                           \
      acc[2][0] += a4.z*b4.x; acc[2][1] += a4.z*b4.y;                           \
      acc[2][2] += a4.z*b4.z; acc[2][3] += a4.z*b4.w;                           \
      acc[3][0] += a4.w*b4.x; acc[3][1] += a4.w*b4.y;                           \
      acc[3][2] += a4.w*b4.z; acc[3][3] += a4.w*b4.w;                           \
    }                                                                           \
  } while (0)

// 128x128 tile, K=32 slice, bf16x3. LDS row stride 40 u16.
#define MFMA_TILE()                                                              \
  do {                                                                           \
    bf8 aH[4], aL[4], bH[4], bL[4];                                              \
    _Pragma("unroll")                                                            \
    for (int i = 0; i < 4; ++i) {                                                \
      const int ar = (wm*64 + i*16 + l15)*40 + quad*8;                           \
      aH[i] = *(const bf8*)&Ah[ar]; aL[i] = *(const bf8*)&Al[ar];                \
      const int br = (wn*64 + i*16 + l15)*40 + quad*8;                           \
      bH[i] = *(const bf8*)&Bh[br]; bL[i] = *(const bf8*)&Bl[br];                \
    }                                                                            \
    _Pragma("unroll")                                                            \
    for (int i = 0; i < 4; ++i)                                                  \
      _Pragma("unroll")                                                          \
      for (int j = 0; j < 4; ++j) {                                              \
        acc[i][j] = __builtin_amdgcn_mfma_f32_16x16x32_bf16(aH[i], bH[j], acc[i][j], 0, 0, 0); \
        acc[i][j] = __builtin_amdgcn_mfma_f32_16x16x32_bf16(aH[i], bL[j], acc[i][j], 0, 0, 0); \
        acc[i][j] = __builtin_amdgcn_mfma_f32_16x16x32_bf16(aL[i], bH[j], acc[i][j], 0, 0, 0); \
      }                                                                          \
  } while (0)

// Transpose + split weights: in (K x N fp32) -> outH/outL (N x K bf16).
__global__ __launch_bounds__(256)
void tconv_kernel(const float* __restrict__ in, u16* __restrict__ outH,
                  u16* __restrict__ outL, int K, int N)
{
    __shared__ float T[64][65];
    const int n0 = blockIdx.x * 64, k0 = blockIdx.y * 64;
    const int t = threadIdx.x;
    const int r = t >> 2, c0 = (t & 3) * 16;
#pragma unroll
    for (int i = 0; i < 4; ++i) {
        const float4 v = *(const float4*)&in[(size_t)(k0 + r) * N + n0 + c0 + 4*i];
        T[r][c0 + 4*i + 0] = v.x; T[r][c0 + 4*i + 1] = v.y;
        T[r][c0 + 4*i + 2] = v.z; T[r][c0 + 4*i + 3] = v.w;
    }
    __syncthreads();
    const int n = t >> 2, ck = (t & 3) * 16;
    u16x8 h0, h1, l0, l1;
#pragma unroll
    for (int i = 0; i < 8; ++i) { u16 h, l; splitf(T[ck + i][n], h, l); h0[i] = h; l0[i] = l; }
#pragma unroll
    for (int i = 0; i < 8; ++i) { u16 h, l; splitf(T[ck + 8 + i][n], h, l); h1[i] = h; l1[i] = l; }
    const size_t ob = (size_t)(n0 + n) * K + k0 + ck;
    *(u16x8*)&outH[ob] = h0; *(u16x8*)&outH[ob + 8] = h1;
    *(u16x8*)&outL[ob] = l0; *(u16x8*)&outL[ob + 8] = l1;
}

// Reservoir step on bf16 hi/lo state planes (row = b*512 + 4w + class).
// K-loop register-prefetches the next slice; epilogue via LDS (coalesced u16x8).
__global__ __launch_bounds__(256)
void step_mfma_kernel(u16* __restrict__ Sh, u16* __restrict__ Sl,
                      const float* __restrict__ X,
                      const u16* __restrict__ WTh, const u16* __restrict__ WTl,
                      const u16* __restrict__ WinTh, const u16* __restrict__ WinTl,
                      int cin, int cout, int s)
{
    __shared__ u16 LB[4 * 128 * 40];          // 40 KB, aliased below
    u16* Ah = LB;
    u16* Al = LB + 5120;
    u16* Bh = LB + 10240;
    u16* Bl = LB + 15360;
    float* Cf = (float*)LB;                   // 64x128 f32 = 32 KB (epilogue)

    const int tid = threadIdx.x;
    const int q0  = blockIdx.x * 128;         // reservoir-col tile
    const int b   = blockIdx.y;
    const int bofs = b * Tt;
    const int wid = tid >> 6, lane = tid & 63;
    const int wm = wid & 1, wn = wid >> 1;
    const int l15 = lane & 15, quad = lane >> 4;
    const int row  = tid & 127;               // staging row within 128-tile
    const int pick = tid >> 7;                // 0: A-operand (state), 1: B (W)

    f32x4 acc[4][4];
    const f32x4 zz = {0.f, 0.f, 0.f, 0.f};
#pragma unroll
    for (int i = 0; i < 4; ++i)
#pragma unroll
        for (int j = 0; j < 4; ++j) acc[i][j] = zz;

    u16* dH = (pick ? Bh : Ah) + row * 40;
    u16* dL = (pick ? Bl : Al) + row * 40;

    if (s > 0) {
        const size_t gr = pick ? (size_t)(q0 + row) * RES
                               : (size_t)(bofs + 4 * row + cin) * RES;
        const u16* gH = (pick ? WTh : Sh) + gr;
        const u16* gL = (pick ? WTl : Sl) + gr;
        u16x8 rh0, rh1, rh2, rh3, rl0, rl1, rl2, rl3;
#define LDK(K0)                                                                 \
        rh0 = *(const u16x8*)&gH[(K0) + 0];  rh1 = *(const u16x8*)&gH[(K0) + 8];\
        rh2 = *(const u16x8*)&gH[(K0) + 16]; rh3 = *(const u16x8*)&gH[(K0) + 24];\
        rl0 = *(const u16x8*)&gL[(K0) + 0];  rl1 = *(const u16x8*)&gL[(K0) + 8];\
        rl2 = *(const u16x8*)&gL[(K0) + 16]; rl3 = *(const u16x8*)&gL[(K0) + 24];
        LDK(0)
        for (int k0 = 0; k0 < RES; k0 += 32) {
            if (k0) __syncthreads();
            *(u16x8*)&dH[0]  = rh0; *(u16x8*)&dH[8]  = rh1;
            *(u16x8*)&dH[16] = rh2; *(u16x8*)&dH[24] = rh3;
            *(u16x8*)&dL[0]  = rl0; *(u16x8*)&dL[8]  = rl1;
            *(u16x8*)&dL[16] = rl2; *(u16x8*)&dL[24] = rl3;
            __syncthreads();
            if (k0 + 32 < RES) { LDK(k0 + 32) }
            MFMA_TILE();
        }
        __syncthreads();
#undef LDK
    }

    // input projection: K=128 over x[b, 4w+s-2, :] @ Win
    for (int k0 = 0; k0 < INd; k0 += 32) {
        if (pick == 0) {
            const int t = 4 * row + s - 2;
            u16x8 h0 = {0,0,0,0,0,0,0,0}, h1 = h0, h2 = h0, h3 = h0;
            u16x8 l0 = h0, l1 = h0, l2 = h0, l3 = h0;
            if (t >= 0) {
                const float* xr = X + (size_t)(bofs + t) * INd + k0;
                const float4 f0 = *(const float4*)&xr[0];
                const float4 f1 = *(const float4*)&xr[4];
                const float4 f2 = *(const float4*)&xr[8];
                const float4 f3 = *(const float4*)&xr[12];
                const float4 f4 = *(const float4*)&xr[16];
                const float4 f5 = *(const float4*)&xr[20];
                const float4 f6 = *(const float4*)&xr[24];
                const float4 f7 = *(const float4*)&xr[28];
                split8(f0, f1, h0, l0); split8(f2, f3, h1, l1);
                split8(f4, f5, h2, l2); split8(f6, f7, h3, l3);
            }
            *(u16x8*)&dH[0] = h0;  *(u16x8*)&dH[8] = h1;
            *(u16x8*)&dH[16] = h2; *(u16x8*)&dH[24] = h3;
            *(u16x8*)&dL[0] = l0;  *(u16x8*)&dL[8] = l1;
            *(u16x8*)&dL[16] = l2; *(u16x8*)&dL[24] = l3;
        } else {
            const size_t gr = (size_t)(q0 + row) * INd + k0;
            *(u16x8*)&dH[0]  = *(const u16x8*)&WinTh[gr];
            *(u16x8*)&dH[8]  = *(const u16x8*)&WinTh[gr + 8];
            *(u16x8*)&dH[16] = *(const u16x8*)&WinTh[gr + 16];
            *(u16x8*)&dH[24] = *(const u16x8*)&WinTh[gr + 24];
            *(u16x8*)&dL[0]  = *(const u16x8*)&WinTl[gr];
            *(u16x8*)&dL[8]  = *(const u16x8*)&WinTl[gr + 8];
            *(u16x8*)&dL[16] = *(const u16x8*)&WinTl[gr + 16];
            *(u16x8*)&dL[24] = *(const u16x8*)&WinTl[gr + 24];
        }
        __syncthreads();
        MFMA_TILE();
        __syncthreads();
    }

    // epilogue via LDS: all global I/O is coalesced u16x8.
    for (int h = 0; h < 2; ++h) {
        __syncthreads();
        if (wm == h) {
#pragma unroll
            for (int i = 0; i < 4; ++i)
#pragma unroll
                for (int j = 0; j < 4; ++j)
#pragma unroll
                    for (int rg = 0; rg < 4; ++rg)
                        Cf[(i * 16 + quad * 4 + rg) * 128 + wn * 64 + j * 16 + l15]
                            = acc[i][j][rg];
        }
        __syncthreads();
#pragma unroll
        for (int pass = 0; pass < 4; ++pass) {
            const int r  = (tid >> 4) + pass * 16;      // 0..63
            const int c0 = (tid & 15) * 8;              // 0..120
            const int wrow = h * 64 + r;
            const float4 v0 = *(const float4*)&Cf[r * 128 + c0];
            const float4 v1 = *(const float4*)&Cf[r * 128 + c0 + 4];
            float vv[8] = {v0.x, v0.y, v0.z, v0.w, v1.x, v1.y, v1.z, v1.w};
            u16x8 ph, pl;
            if (s > 0) {
                const size_t prow = (size_t)(bofs + 4 * wrow + cin) * RES + q0 + c0;
                ph = *(const u16x8*)&Sh[prow];
                pl = *(const u16x8*)&Sl[prow];
            }
            u16x8 oh, ol;
#pragma unroll
            for (int e = 0; e < 8; ++e) {
                float prev = (s > 0) ? (bf2f(ph[e]) + bf2f(pl[e])) : 0.f;
                float v = 0.7f * prev + 0.3f * sinf(vv[e]);
                u16 hh, ll; splitf(v, hh, ll);
                oh[e] = hh; ol[e] = ll;
            }
            const size_t orow = (size_t)(bofs + 4 * wrow + cout) * RES + q0 + c0;
            *(u16x8*)&Sh[orow] = oh;
            *(u16x8*)&Sl[orow] = ol;
        }
    }
}

// Gram on bf16 planes: A[b] = (Sh+Sl)(Sh+Sl)^T + ones + reg*I, bf16x3.
__global__ __launch_bounds__(256)
void gram_mfma_kernel(const u16* __restrict__ Sh, const u16* __restrict__ Sl,
                      float* __restrict__ A, const float* __restrict__ lam)
{
    __shared__ u16 LB[4 * 128 * 40];
    u16* Ah = LB;
    u16* Al = LB + 5120;
    u16* Bh = LB + 10240;
    u16* Bl = LB + 15360;
    float* Cf = (float*)LB;                   // 64 x 132 f32 = 33.8 KB

    const int tid = threadIdx.x;
    const int bt  = blockIdx.y;
    int ti = 0, rem = (int)blockIdx.x;
    while (rem >= 4 - ti) { rem -= 4 - ti; ++ti; }
    const int tj = ti + rem;
    const int n0 = ti * 128, m0 = tj * 128;
    const int bofs = bt * Tt;

    const int wid = tid >> 6, lane = tid & 63;
    const int wm = wid & 1, wn = wid >> 1;
    const int l15 = lane & 15, quad = lane >> 4;
    const int row  = tid & 127;
    const int pick = tid >> 7;

    f32x4 acc[4][4];
    const f32x4 zz = {0.f, 0.f, 0.f, 0.f};
#pragma unroll
    for (int i = 0; i < 4; ++i)
#pragma unroll
        for (int j = 0; j < 4; ++j) acc[i][j] = zz;

    u16* dH = (pick ? Bh : Ah) + row * 40;
    u16* dL = (pick ? Bl : Al) + row * 40;
    const size_t gr = (size_t)(bofs + (pick ? m0 : n0) + row) * RES;
    const u16* gH = Sh + gr;
    const u16* gL = Sl + gr;

    u16x8 rh0, rh1, rh2, rh3, rl0, rl1, rl2, rl3;
#define LDK(K0)                                                                 \
    rh0 = *(const u16x8*)&gH[(K0) + 0];  rh1 = *(const u16x8*)&gH[(K0) + 8];    \
    rh2 = *(const u16x8*)&gH[(K0) + 16]; rh3 = *(const u16x8*)&gH[(K0) + 24];   \
    rl0 = *(const u16x8*)&gL[(K0) + 0];  rl1 = *(const u16x8*)&gL[(K0) + 8];    \
    rl2 = *(const u16x8*)&gL[(K0) + 16]; rl3 = *(const u16x8*)&gL[(K0) + 24];
    LDK(0)
    for (int k0 = 0; k0 < RES; k0 += 32) {
        if (k0) __syncthreads();
        *(u16x8*)&dH[0]  = rh0; *(u16x8*)&dH[8]  = rh1;
        *(u16x8*)&dH[16] = rh2; *(u16x8*)&dH[24] = rh3;
        *(u16x8*)&dL[0]  = rl0; *(u16x8*)&dL[8]  = rl1;
        *(u16x8*)&dL[16] = rl2; *(u16x8*)&dL[24] = rl3;
        __syncthreads();
        if (k0 + 32 < RES) { LDK(k0 + 32) }
        MFMA_TILE();
    }
#undef LDK

    const float reg = log1pf(expf(lam[0]));
    float* Ab = A + (size_t)bt * 512 * 512;
    for (int h = 0; h < 2; ++h) {
        __syncthreads();
        if (wm == h) {
#pragma unroll
            for (int i = 0; i < 4; ++i)
#pragma unroll
                for (int j = 0; j < 4; ++j)
#pragma unroll
                    for (int rg = 0; rg < 4; ++rg)
                        Cf[(i * 16 + quad * 4 + rg) * 132 + wn * 64 + j * 16 + l15]
                            = acc[i][j][rg];
        }
        __syncthreads();
        // row-major half: rows nn = n0+h*64+r, cols m0..m0+127
#pragma unroll
        for (int pass = 0; pass < 4; ++pass) {
            const int r  = (tid >> 4) + pass * 16;
            const int c0 = (tid & 15) * 8;
            const int nn = n0 + h * 64 + r;
            float o[8];
#pragma unroll
            for (int e = 0; e < 8; ++e) {
                const int mm = m0 + c0 + e;
                float v = Cf[r * 132 + c0 + e] + 1.0f;
                if (nn == mm) v += reg;
                o[e] = v;
            }
            float* dst = Ab + (size_t)nn * 512 + m0 + c0;
            *(float4*)&dst[0] = make_float4(o[0], o[1], o[2], o[3]);
            *(float4*)&dst[4] = make_float4(o[4], o[5], o[6], o[7]);
        }
        // transposed half: rows mm = m0+rt, cols n0+h*64 .. +63
#pragma unroll
        for (int pass = 0; pass < 4; ++pass) {
            const int rt  = (tid >> 3) + pass * 32;     // 0..127
            const int c0t = (tid & 7) * 8;              // 0..56
            const int mm  = m0 + rt;
            float o[8];
#pragma unroll
            for (int e = 0; e < 8; ++e) {
                const int nn = n0 + h * 64 + c0t + e;
                float v = Cf[(c0t + e) * 132 + rt] + 1.0f;
                if (nn == mm) v += reg;
                o[e] = v;
            }
            float* dst = Ab + (size_t)mm * 512 + n0 + h * 64 + c0t;
            *(float4*)&dst[0] = make_float4(o[0], o[1], o[2], o[3]);
            *(float4*)&dst[4] = make_float4(o[4], o[5], o[6], o[7]);
        }
    }
}

// Diag-block Cholesky (64x64) + inverse, one wave per batch.
__global__ __launch_bounds__(64)
void chol_diag_inv_kernel(float* __restrict__ Aall, float* __restrict__ Winv,
                          float* __restrict__ WinvT, int k)
{
    __shared__ float P[64][65];
    __shared__ float W[64][65];
    const int b = blockIdx.x, c = threadIdx.x;
    float* A = Aall + (size_t)b * 512 * 512;
    const int j0 = 64 * k;

    for (int m = 0; m < 64; m += 4) {
        const float4 v = *(const float4*)(A + (size_t)(j0 + c) * 512 + j0 + m);
        P[c][m] = v.x; P[c][m+1] = v.y; P[c][m+2] = v.z; P[c][m+3] = v.w;
    }
    __syncthreads();
    for (int j = 0; j < 64; ++j) {
        const float d = sqrtf(P[j][j]);
        if (c >= j) P[c][j] = (c == j) ? d : P[c][j] / d;
        __syncthreads();
        const float pj = (c > j) ? P[c][j] : 0.f;
        for (int m = j + 1; m <= c; ++m) P[c][m] -= pj * P[m][j];
        __syncthreads();
    }
    for (int j = 0; j < 64; ++j) {
        float sv = (j == c) ? 1.f : 0.f;
        for (int m = c; m < j; ++m) sv -= P[j][m] * W[m][c];
        W[j][c] = (j >= c) ? sv / P[j][j] : 0.f;
    }
    __syncthreads();
    for (int m = 0; m < 64; m += 4)
        *(float4*)(A + (size_t)(j0 + c) * 512 + j0 + m) =
            make_float4(P[c][m], P[c][m+1], P[c][m+2], P[c][m+3]);
    float* Wo  = Winv  + ((size_t)b * 8 + k) * 64 * 64;
    float* WoT = WinvT + ((size_t)b * 8 + k) * 64 * 64;
    for (int j = 0; j < 64; ++j) Wo[(size_t)j * 64 + c] = W[j][c];
    for (int m = 0; m < 64; m += 4)
        *(float4*)(WoT + (size_t)c * 64 + m) =
            make_float4(W[m][c], W[m+1][c], W[m+2][c], W[m+3][c]);
}

// Panel TRSM via inverse: L[i0.., k] = A[i0.., k] @ W^T
__global__ __launch_bounds__(256)
void trsm_kernel(float* __restrict__ Aall, const float* __restrict__ WinvT, int k)
{
    __shared__ float St[BK][BM + 4];
    __shared__ float Wt[BK][BN + 4];
    float* A = Aall + (size_t)blockIdx.y * 512 * 512;
    const float* WT = WinvT + ((size_t)blockIdx.y * 8 + k) * 64 * 64;
    const int i0 = (k + 1 + blockIdx.x) * 64, p0 = k * 64;
    const int tid = threadIdx.x;
    const int li = tid >> 2, lk = (tid & 3) << 2;
    const int wk = tid >> 4, wq = (tid & 15) << 2;
    const int ty = tid >> 4, tx = tid & 15;
    float acc[4][4] = {};
    for (int k0 = 0; k0 < 64; k0 += BK) {
        const float4 u = *(const float4*)(A + (size_t)(i0 + li) * 512 + p0 + k0 + lk);
        St[lk + 0][li] = u.x; St[lk + 1][li] = u.y;
        St[lk + 2][li] = u.z; St[lk + 3][li] = u.w;
        *(float4*)&Wt[wk][wq] = *(const float4*)(WT + (size_t)(k0 + wk) * 64 + wq);
        __syncthreads();
        MICRO(St, Wt);
        __syncthreads();
    }
#pragma unroll
    for (int a = 0; a < 4; ++a) {
        const int r = i0 + (ty << 2) + a;
        *(float4*)(A + (size_t)r * 512 + p0 + (tx << 2)) =
            make_float4(acc[a][0], acc[a][1], acc[a][2], acc[a][3]);
    }
}

// Trailing update: A[ti,tj] -= L[ti,k] L[tj,k]^T
__global__ __launch_bounds__(256)
void chol_trailing_kernel(float* __restrict__ Aall, int k)
{
    __shared__ float Ut[BK][BM + 4];
    __shared__ float Vt[BK][BN + 4];
    float* A = Aall + (size_t)blockIdx.y * 512 * 512;
    const int tid = threadIdx.x;
    int a = 0, rem = (int)blockIdx.x;
    while (rem >= a + 1) { rem -= a + 1; ++a; }
    const int ti = k + 1 + a, tj = k + 1 + rem;
    const int i0 = ti * 64, j0c = tj * 64, p0 = k * 64;

    const int li = tid >> 2, lk = (tid & 3) << 2;
    const int ty = tid >> 4, tx = tid & 15;
    float acc[4][4] = {};

    for (int k0 = 0; k0 < 64; k0 += BK) {
        const float4 u = *(const float4*)(A + (size_t)(i0 + li) * 512 + p0 + k0 + lk);
        const float4 v = *(const float4*)(A + (size_t)(j0c + li) * 512 + p0 + k0 + lk);
        Ut[lk + 0][li] = u.x; Ut[lk + 1][li] = u.y;
        Ut[lk + 2][li] = u.z; Ut[lk + 3][li] = u.w;
        Vt[lk + 0][li] = v.x; Vt[lk + 1][li] = v.y;
        Vt[lk + 2][li] = v.z; Vt[lk + 3][li] = v.w;
        __syncthreads();
        MICRO(Ut, Vt);
        __syncthreads();
    }
#pragma unroll
    for (int aa = 0; aa < 4; ++aa) {
        const int r = i0 + (ty << 2) + aa;
        float* crow = A + (size_t)r * 512 + j0c + (tx << 2);
        float4 cv = *(const float4*)crow;
        cv.x -= acc[aa][0]; cv.y -= acc[aa][1];
        cv.z -= acc[aa][2]; cv.w -= acc[aa][3];
        *(float4*)crow = cv;
    }
}

// Blocked fwd+bwd solve via diag-block inverses.
// BK=32 A-GEMM loops (half the barriers) + register prefetch of the next tile.
__global__ __launch_bounds__(256)
void fb_solve2_kernel(const float* __restrict__ Aall,
                      const float* __restrict__ Winv,
                      const float* __restrict__ WinvT,
                      const float* __restrict__ Y, float* __restrict__ Zall)
{
    __shared__ float V[512][64];          // 128 KB
    __shared__ float St[32][68];          // 8.7 KB (BK=32 A tile)
    __shared__ float Wt[BK][68];          // 4.3 KB
    __shared__ float Ush[64][68];         // 17.4 KB   total 161.5 KB < 160 KiB cap
    const int b   = blockIdx.x, tid = threadIdx.x;
    const float* A   = Aall + (size_t)b * 512 * 512;
    const float* Yb  = Y    + (size_t)b * 512 * OUTd;
    float* Z         = Zall + (size_t)b * 512 * OUTd;
    const float* Wb  = Winv  + (size_t)b * 8 * 64 * 64;
    const float* WbT = WinvT + (size_t)b * 8 * 64 * 64;

    const int li8 = tid >> 2, lk8 = (tid & 3) << 3;   // fwd: 64 rows x 32 cols
    const int rr8 = tid >> 3, cc8 = (tid & 7) << 3;   // bwd: 32 rows x 64 cols
    const int wk = tid >> 4, wq = (tid & 15) << 2;
    const int ty = tid >> 4, tx = tid & 15;

    for (int t = tid; t < 512 * 16; t += 256) {
        const int row = t >> 4, c4 = (t & 15) << 2;
        *(float4*)&V[row][c4] = *(const float4*)(Yb + (size_t)row * 64 + c4);
    }
    __syncthreads();

    // ---- forward: V_k = W_k (Y_k - L[k, 0:64k] @ V) ----
    for (int k = 0; k < 8; ++k) {
        const int r0 = k * 64;
        float acc[4][4] = {};
        float4 pA0, pA1;
        if (r0 > 0) {
            pA0 = *(const float4*)(A + (size_t)(r0 + li8) * 512 + lk8);
            pA1 = *(const float4*)(A + (size_t)(r0 + li8) * 512 + lk8 + 4);
        }
        for (int k0 = 0; k0 < r0; k0 += 32) {
            if (k0) __syncthreads();
            St[lk8 + 0][li8] = pA0.x; St[lk8 + 1][li8] = pA0.y;
            St[lk8 + 2][li8] = pA0.z; St[lk8 + 3][li8] = pA0.w;
            St[lk8 + 4][li8] = pA1.x; St[lk8 + 5][li8] = pA1.y;
            St[lk8 + 6][li8] = pA1.z; St[lk8 + 7][li8] = pA1.w;
            __syncthreads();
            if (k0 + 32 < r0) {
                pA0 = *(const float4*)(A + (size_t)(r0 + li8) * 512 + k0 + 32 + lk8);
                pA1 = *(const float4*)(A + (size_t)(r0 + li8) * 512 + k0 + 32 + lk8 + 4);
            }
            MICRO(St, (V + k0));
            MICRO((St + 16), (V + k0 + 16));
        }
        if (r0) __syncthreads();
#pragma unroll
        for (int a = 0; a < 4; ++a)
#pragma unroll
            for (int c = 0; c < 4; ++c)
                Ush[(ty << 2) + a][(tx << 2) + c] =
                    V[r0 + (ty << 2) + a][(tx << 2) + c] - acc[a][c];
        __syncthreads();
        float acc2[4][4] = {};
        const float* WTk = WbT + (size_t)k * 64 * 64;
        for (int k0 = 0; k0 < 64; k0 += BK) {
            *(float4*)&Wt[wk][wq] = *(const float4*)(WTk + (size_t)(k0 + wk) * 64 + wq);
            __syncthreads();
            {
                float (*acc)[4] = acc2;
                MICRO(Wt, (Ush + k0));
            }
            __syncthreads();
        }
#pragma unroll
        for (int a = 0; a < 4; ++a)
#pragma unroll
            for (int c = 0; c < 4; ++c)
                V[r0 + (ty << 2) + a][(tx << 2) + c] = acc2[a][c];
        __syncthreads();
    }

    // ---- backward: Z_k = W_k^T (V_k - L[64(k+1):, k]^T @ Z) ----
    for (int k = 7; k >= 0; --k) {
        const int r0 = k * 64;
        float acc[4][4] = {};
        float4 pB0, pB1;
        if (r0 + 64 < 512) {
            pB0 = *(const float4*)(A + (size_t)(r0 + 64 + rr8) * 512 + r0 + cc8);
            pB1 = *(const float4*)(A + (size_t)(r0 + 64 + rr8) * 512 + r0 + cc8 + 4);
        }
        for (int m0 = r0 + 64; m0 < 512; m0 += 32) {
            if (m0 > r0 + 64) __syncthreads();
            *(float4*)&St[rr8][cc8]     = pB0;
            *(float4*)&St[rr8][cc8 + 4] = pB1;
            __syncthreads();
            if (m0 + 32 < 512) {
                pB0 = *(const float4*)(A + (size_t)(m0 + 32 + rr8) * 512 + r0 + cc8);
                pB1 = *(const float4*)(A + (size_t)(m0 + 32 + rr8) * 512 + r0 + cc8 + 4);
            }
            MICRO(St, (V + m0));
            MICRO((St + 16), (V + m0 + 16));
        }
        if (r0 + 64 < 512) __syncthreads();
#pragma unroll
        for (int a = 0; a < 4; ++a)
#pragma unroll
            for (int c = 0; c < 4; ++c)
                Ush[(ty << 2) + a][(tx << 2) + c] =
                    V[r0 + (ty << 2) + a][(tx << 2) + c] - acc[a][c];
        __syncthreads();
        float acc2[4][4] = {};
        const float* Wk = Wb + (size_t)k * 64 * 64;
        for (int k0 = 0; k0 < 64; k0 += BK) {
            *(float4*)&Wt[wk][wq] = *(const float4*)(Wk + (size_t)(k0 + wk) * 64 + wq);
            __syncthreads();
            {
                float (*acc)[4] = acc2;
                MICRO(Wt, (Ush + k0));
            }
            __syncthreads();
        }
#pragma unroll
        for (int a = 0; a < 4; ++a)
#pragma unroll
            for (int c = 0; c < 4; ++c)
                V[r0 + (ty << 2) + a][(tx << 2) + c] = acc2[a][c];
        __syncthreads();
    }

    for (int t = tid; t < 512 * 16; t += 256) {
        const int row = t >> 4, c4 = (t & 15) << 2;
        *(float4*)(Z + (size_t)row * 64 + c4) = *(const float4*)&V[row][c4];
    }
}

// w[b] = RS_b^T @ Z_b, RS reconstructed as h+l.
__global__ __launch_bounds__(256)
void out_kernel(const u16* __restrict__ Sh, const u16* __restrict__ Sl,
                const float* __restrict__ Z, float* __restrict__ Wout)
{
    __shared__ float Rt[BK][64 + 4];
    __shared__ float Zt[BK][64 + 4];
    const int tid = threadIdx.x;
    const int b   = blockIdx.y;
    const int d0  = blockIdx.x * 64;
    const int kk  = tid >> 4, cq = (tid & 15) << 2;
    const int ty  = tid >> 4, tx = tid & 15;
    float acc[4][4] = {};

    for (int k0 = 0; k0 < Tt; k0 += BK) {
        const size_t ri = (size_t)(b * Tt + k0 + kk) * RES + d0 + cq;
        const u16x4 hv = *(const u16x4*)&Sh[ri];
        const u16x4 lv = *(const u16x4*)&Sl[ri];
        Rt[kk][cq + 0] = bf2f(hv[0]) + bf2f(lv[0]);
        Rt[kk][cq + 1] = bf2f(hv[1]) + bf2f(lv[1]);
        Rt[kk][cq + 2] = bf2f(hv[2]) + bf2f(lv[2]);
        Rt[kk][cq + 3] = bf2f(hv[3]) + bf2f(lv[3]);
        *(float4*)&Zt[kk][cq] =
            *(const float4*)(Z + ((size_t)b * Tt + k0 + kk) * OUTd + cq);
        __syncthreads();
        MICRO(Rt, Zt);
        __syncthreads();
    }
#pragma unroll
    for (int a = 0; a < 4; ++a) {
        const int d = d0 + (ty << 2) + a;
        *(float4*)(Wout + ((size_t)b * RES + d) * OUTd + (tx << 2)) =
            make_float4(acc[a][0], acc[a][1], acc[a][2], acc[a][3]);
    }
}

__global__ __launch_bounds__(64)
void bias_kernel(const float* __restrict__ Z, float* __restrict__ Bout)
{
    const int b = blockIdx.x, o = threadIdx.x;
    const float* Zb = Z + (size_t)b * Tt * OUTd;
    float s = 0.f;
    for (int n = 0; n < Tt; ++n) s += Zb[(size_t)n * OUTd + o];
    Bout[(size_t)b * OUTd + o] = s;
}

extern "C" void kernel_launch(void* const* d_in, const int* in_sizes, int n_in,
                              void* d_out, int out_size, void* d_ws, size_t ws_size,
                              hipStream_t stream)
{
    const float* X    = (const float*)d_in[0];   // (32,512,128)
    const float* Y    = (const float*)d_in[1];   // (32,512,64)
    const float* Wres = (const float*)d_in[2];   // (2048,2048)
    const float* Win  = (const float*)d_in[3];   // (128,2048)
    const float* lam  = (const float*)d_in[4];   // scalar

    float* out  = (float*)d_out;
    float* Wout = out;
    float* Bout = out + (size_t)Bb * RES * OUTd;

    // ws: Sh 64 | Sl 64 | WTh 8 | WTl 8 | WinTh .5 | WinTl .5 | A 32 | Z 4 | Wi 4 | WiT 4 = 189 MB
    char* p = (char*)d_ws;
    u16* Sh    = (u16*)p;   p += (size_t)Bb * Tt * RES * 2;
    u16* Sl    = (u16*)p;   p += (size_t)Bb * Tt * RES * 2;
    u16* WTh   = (u16*)p;   p += (size_t)RES * RES * 2;
    u16* WTl   = (u16*)p;   p += (size_t)RES * RES * 2;
    u16* WinTh = (u16*)p;   p += (size_t)INd * RES * 2;
    u16* WinTl = (u16*)p;   p += (size_t)INd * RES * 2;
    float* A   = (float*)p; p += (size_t)Bb * 512 * 512 * 4;
    float* Z   = (float*)p; p += (size_t)Bb * Tt * OUTd * 4;
    float* Wi  = (float*)p; p += (size_t)Bb * 8 * 64 * 64 * 4;
    float* WiT = (float*)p;

    const dim3 blk(256);
    tconv_kernel<<<dim3(RES / 64, RES / 64), blk, 0, stream>>>(Wres, WTh, WTl, RES, RES);
    tconv_kernel<<<dim3(RES / 64, INd / 64), blk, 0, stream>>>(Win, WinTh, WinTl, INd, RES);

    // classes: s:(cin->cout) 0:(-,2) 1:(2,1) 2:(1,0) 3:(0,1) 4:(1,2) 5:(2,3)
    const dim3 sgrid(RES / 128, Bb);
    step_mfma_kernel<<<sgrid, blk, 0, stream>>>(Sh, Sl, X, WTh, WTl, WinTh, WinTl, 0, 2, 0);
    step_mfma_kernel<<<sgrid, blk, 0, stream>>>(Sh, Sl, X, WTh, WTl, WinTh, WinTl, 2, 1, 1);
    step_mfma_kernel<<<sgrid, blk, 0, stream>>>(Sh, Sl, X, WTh, WTl, WinTh, WinTl, 1, 0, 2);
    step_mfma_kernel<<<sgrid, blk, 0, stream>>>(Sh, Sl, X, WTh, WTl, WinTh, WinTl, 0, 1, 3);
    step_mfma_kernel<<<sgrid, blk, 0, stream>>>(Sh, Sl, X, WTh, WTl, WinTh, WinTl, 1, 2, 4);
    step_mfma_kernel<<<sgrid, blk, 0, stream>>>(Sh, Sl, X, WTh, WTl, WinTh, WinTl, 2, 3, 5);

    gram_mfma_kernel<<<dim3(10, Bb), blk, 0, stream>>>(Sh, Sl, A, lam);

    for (int k = 0; k < 8; ++k) {
        chol_diag_inv_kernel<<<dim3(Bb), dim3(64), 0, stream>>>(A, Wi, WiT, k);
        if (k < 7) {
            trsm_kernel<<<dim3(7 - k, Bb), blk, 0, stream>>>(A, WiT, k);
            const int m = 7 - k;
            chol_trailing_kernel<<<dim3(m * (m + 1) / 2, Bb), blk, 0, stream>>>(A, k);
        }
    }
    fb_solve2_kernel<<<dim3(Bb), blk, 0, stream>>>(A, Wi, WiT, Y, Z);

    out_kernel<<<dim3(RES / 64, Bb), blk, 0, stream>>>(Sh, Sl, Z, Wout);
    bias_kernel<<<dim3(Bb), dim3(OUTd), 0, stream>>>(Z, Bout);
}